// Round 1
// baseline (1130.276 us; speedup 1.0000x reference)
//
#include <hip/hip_runtime.h>
#include <stdio.h>
#include <stdint.h>

// Problem constants
#define BB 2
#define SS 2048
#define ED 1024
#define HH 16
#define HDD 64
#define MROWS 4096            // BB*SS
#define NW_ELEM 1048576u      // ED*ED

// ws layout (bytes)
#define WEFF_OFF   0u                    // 4 x 4MiB f32
#define F_REGION   (6u*16777216u)        // weff,qn,Q,K,V,ctx : 96 MiB
#define HIST_OFF   F_REGION              // 4*256*4 = 4096
#define PABS_OFF   (HIST_OFF + 4096u)    // 4*256*8 = 8192
#define PMASK_OFF  (PABS_OFF + 8192u)
#define PCNT_OFF   (PMASK_OFF + 8192u)   // 4*256*4 = 4096
#define STATS_OFF  (PCNT_OFF + 4096u)
#define WS_NEEDED  (STATS_OFF + 256u)

struct Stats {
  double sumAbs;
  double sumMasked;
  float thr;
  float scale;
  unsigned count;
  unsigned prefix;
  unsigned kcur;
  unsigned pad;
};

__device__ __forceinline__ const float* wsel(int w, const float* W0, const float* W1,
                                             const float* W2, const float* W3) {
  return w == 0 ? W0 : w == 1 ? W1 : w == 2 ? W2 : W3;
}

// ---------- pass 1: sum |W| (block partials, fp64, deterministic) ----------
__global__ __launch_bounds__(256) void k_abs_partial(const float* W0, const float* W1,
                                                     const float* W2, const float* W3,
                                                     double* pAbs) {
  const int w = blockIdx.y, t = threadIdx.x;
  const float* W = wsel(w, W0, W1, W2, W3) + blockIdx.x * 4096;
  double s = 0.0;
#pragma unroll
  for (int r = 0; r < 4; r++) {
    float4 v = *(const float4*)(W + (t + 256 * r) * 4);
    s += (double)fabsf(v.x); s += (double)fabsf(v.y);
    s += (double)fabsf(v.z); s += (double)fabsf(v.w);
  }
  __shared__ double sd[256];
  sd[t] = s;
  __syncthreads();
  for (int off = 128; off > 0; off >>= 1) {
    if (t < off) sd[t] += sd[t + off];
    __syncthreads();
  }
  if (!t) pAbs[w * 256 + blockIdx.x] = sd[0];
}

__global__ void k_fin1(const double* pAbs, Stats* st) {
  const int w = blockIdx.x;
  if (threadIdx.x == 0) {
    double s = 0;
    for (int i = 0; i < 256; i++) s += pAbs[w * 256 + i];
    st[w].sumAbs = s;
    st[w].thr = 0.7f * (float)(s * (1.0 / 1048576.0));
  }
}

// ---------- pass 2: sum/count of |W| above thr ----------
__global__ __launch_bounds__(256) void k_masked_partial(const float* W0, const float* W1,
                                                        const float* W2, const float* W3,
                                                        const Stats* st, double* pM,
                                                        unsigned* pC) {
  const int w = blockIdx.y, t = threadIdx.x;
  const float thr = st[w].thr;
  const float* W = wsel(w, W0, W1, W2, W3) + blockIdx.x * 4096;
  double s = 0.0;
  unsigned c = 0;
#pragma unroll
  for (int r = 0; r < 4; r++) {
    float4 v = *(const float4*)(W + (t + 256 * r) * 4);
    float xs[4] = {v.x, v.y, v.z, v.w};
#pragma unroll
    for (int q = 0; q < 4; q++) {
      float a = fabsf(xs[q]);
      if (a > thr) { s += (double)a; c++; }
    }
  }
  __shared__ double sd[256];
  __shared__ unsigned sc[256];
  sd[t] = s; sc[t] = c;
  __syncthreads();
  for (int off = 128; off > 0; off >>= 1) {
    if (t < off) { sd[t] += sd[t + off]; sc[t] += sc[t + off]; }
    __syncthreads();
  }
  if (!t) { pM[w * 256 + blockIdx.x] = sd[0]; pC[w * 256 + blockIdx.x] = sc[0]; }
}

__global__ void k_fin2(const double* pM, const unsigned* pC, Stats* st) {
  const int w = blockIdx.x;
  if (threadIdx.x == 0) {
    double s = 0; unsigned c = 0;
    for (int i = 0; i < 256; i++) { s += pM[w * 256 + i]; c += pC[w * 256 + i]; }
    st[w].sumMasked = s;
    st[w].count = c;
    st[w].scale = (float)s / fmaxf((float)c, 1.0f);
  }
}

// ---------- radix select on |res| bit patterns (exact kth largest) ----------
__global__ __launch_bounds__(256) void k_hist(const float* W0, const float* W1,
                                              const float* W2, const float* W3,
                                              const Stats* st, unsigned* histG, int pass) {
  const int w = blockIdx.y, t = threadIdx.x;
  __shared__ unsigned h[256];
  h[t] = 0;
  __syncthreads();
  const float thr = st[w].thr, scale = st[w].scale;
  const unsigned prefix = st[w].prefix;  // valid for pass>0 only
  const float* W = wsel(w, W0, W1, W2, W3) + blockIdx.x * 4096;
#pragma unroll
  for (int r = 0; r < 4; r++) {
    float4 v = *(const float4*)(W + (t + 256 * r) * 4);
    float xs[4] = {v.x, v.y, v.z, v.w};
#pragma unroll
    for (int q = 0; q < 4; q++) {
      float x = xs[q];
      float a = fabsf(x);
      float wq = (a > thr) ? copysignf(scale, x) : 0.0f;
      unsigned bits = __float_as_uint(fabsf(x - wq));
      if (pass == 0) {
        atomicAdd(&h[bits >> 24], 1u);
      } else {
        if ((bits >> (32 - 8 * pass)) == prefix)
          atomicAdd(&h[(bits >> (24 - 8 * pass)) & 255u], 1u);
      }
    }
  }
  __syncthreads();
  if (h[t]) atomicAdd(&histG[w * 256 + t], h[t]);
}

__global__ void k_scan(unsigned* histG, Stats* st, int pass) {
  const int w = blockIdx.x, t = threadIdx.x;
  __shared__ unsigned h[256];
  h[t] = histG[w * 256 + t];
  __syncthreads();
  if (t == 0) {
    unsigned k = (pass == 0) ? ((w == 3) ? 104857u : 52428u) : st[w].kcur;
    unsigned cum = 0;
    int sel = 0;
    for (int b = 255; b >= 0; b--) {
      cum += h[b];
      if (cum >= k) { sel = b; k -= (cum - h[b]); break; }
    }
    unsigned pfx = (pass == 0) ? 0u : st[w].prefix;
    st[w].prefix = (pfx << 8) | (unsigned)sel;
    st[w].kcur = k;
  }
  __syncthreads();
  histG[w * 256 + t] = 0;  // ready for next pass / next launch
}

// ---------- build W_eff ----------
__global__ __launch_bounds__(256) void k_weff(const float* W0, const float* W1,
                                              const float* W2, const float* W3,
                                              const Stats* st, float* weff) {
  const int w = blockIdx.y;
  const unsigned kth = st[w].prefix;
  const float thr = st[w].thr, scale = st[w].scale;
  const unsigned idx = (blockIdx.x * 256 + threadIdx.x) * 4;
  const float* W = wsel(w, W0, W1, W2, W3);
  float4 v = *(const float4*)(W + idx);
  float xs[4] = {v.x, v.y, v.z, v.w};
  float o[4];
#pragma unroll
  for (int c = 0; c < 4; c++) {
    float x = xs[c];
    float a = fabsf(x);
    float wq = (a > thr) ? copysignf(scale, x) : 0.0f;
    float res = x - wq;
    unsigned bits = __float_as_uint(fabsf(res));
    o[c] = wq + ((bits >= kth) ? res : 0.0f);
  }
  float4 ov = make_float4(o[0], o[1], o[2], o[3]);
  *(float4*)(weff + (size_t)w * NW_ELEM + idx) = ov;
}

// ---------- LayerNorm (query only) ----------
__global__ __launch_bounds__(256) void k_ln(const float* __restrict__ X,
                                            const float* __restrict__ g,
                                            const float* __restrict__ b,
                                            float* __restrict__ Y) {
  const int row = blockIdx.x, t = threadIdx.x;
  __shared__ float red[8];
  float4 v = *(const float4*)&X[(size_t)row * ED + t * 4];
  float s = v.x + v.y + v.z + v.w;
#pragma unroll
  for (int m = 32; m; m >>= 1) s += __shfl_xor(s, m, 64);
  if ((t & 63) == 0) red[t >> 6] = s;
  __syncthreads();
  float mu = (red[0] + red[1] + red[2] + red[3]) * (1.0f / 1024.0f);
  float dx = v.x - mu, dy = v.y - mu, dz = v.z - mu, dw = v.w - mu;
  float s2 = dx * dx + dy * dy + dz * dz + dw * dw;
#pragma unroll
  for (int m = 32; m; m >>= 1) s2 += __shfl_xor(s2, m, 64);
  if ((t & 63) == 0) red[4 + (t >> 6)] = s2;
  __syncthreads();
  float var = (red[4] + red[5] + red[6] + red[7]) * (1.0f / 1024.0f);
  float inv = rsqrtf(var + 1e-5f);
  float4 gg = *(const float4*)&g[t * 4];
  float4 bb = *(const float4*)&b[t * 4];
  float4 o = make_float4(dx * inv * gg.x + bb.x, dy * inv * gg.y + bb.y,
                         dz * inv * gg.z + bb.z, dw * inv * gg.w + bb.w);
  *(float4*)&Y[(size_t)row * ED + t * 4] = o;
}

// ---------- fp32 GEMM: C = A @ W^T + bias, optional route + BHSD layout ----------
// MODE 0: route (|y|>=0.05) + write [B,H,S,HD]   MODE 1: plain [M,N]
template <int MODE>
__global__ __launch_bounds__(256) void k_gemm(const float* __restrict__ A,
                                              const float* __restrict__ Wf,
                                              const float* __restrict__ bias,
                                              float* __restrict__ C) {
  __shared__ float As[16][132];
  __shared__ float Bs[16][132];
  const int t = threadIdx.x;
  const int tx = t & 15, ty = t >> 4;
  const int m0 = blockIdx.y * 128, n0 = blockIdx.x * 128;
  float acc[8][8];
#pragma unroll
  for (int i = 0; i < 8; i++)
#pragma unroll
    for (int j = 0; j < 8; j++) acc[i][j] = 0.0f;

  for (int kt = 0; kt < 64; ++kt) {
#pragma unroll
    for (int r = 0; r < 2; r++) {
      int i = t + 256 * r;
      int row = i >> 2, kq = i & 3;
      float4 av = *(const float4*)&A[(size_t)(m0 + row) * ED + kt * 16 + kq * 4];
      float4 bv = *(const float4*)&Wf[(size_t)(n0 + row) * ED + kt * 16 + kq * 4];
      As[kq * 4 + 0][row] = av.x; As[kq * 4 + 1][row] = av.y;
      As[kq * 4 + 2][row] = av.z; As[kq * 4 + 3][row] = av.w;
      Bs[kq * 4 + 0][row] = bv.x; Bs[kq * 4 + 1][row] = bv.y;
      Bs[kq * 4 + 2][row] = bv.z; Bs[kq * 4 + 3][row] = bv.w;
    }
    __syncthreads();
#pragma unroll
    for (int k = 0; k < 16; k++) {
      float4 a0 = *(const float4*)&As[k][ty * 4];
      float4 a1 = *(const float4*)&As[k][ty * 4 + 64];
      float4 b0 = *(const float4*)&Bs[k][tx * 4];
      float4 b1 = *(const float4*)&Bs[k][tx * 4 + 64];
      float a[8] = {a0.x, a0.y, a0.z, a0.w, a1.x, a1.y, a1.z, a1.w};
      float b[8] = {b0.x, b0.y, b0.z, b0.w, b1.x, b1.y, b1.z, b1.w};
#pragma unroll
      for (int i = 0; i < 8; i++)
#pragma unroll
        for (int j = 0; j < 8; j++) acc[i][j] = fmaf(a[i], b[j], acc[i][j]);
    }
    __syncthreads();
  }

#pragma unroll
  for (int i = 0; i < 8; i++) {
    const int m = m0 + ty * 4 + (i & 3) + (i >> 2) * 64;
#pragma unroll
    for (int jc = 0; jc < 2; jc++) {
      const int n = n0 + tx * 4 + jc * 64;
      const float4 bv = *(const float4*)&bias[n];
      float4 y;
      y.x = acc[i][jc * 4 + 0] + bv.x;
      y.y = acc[i][jc * 4 + 1] + bv.y;
      y.z = acc[i][jc * 4 + 2] + bv.z;
      y.w = acc[i][jc * 4 + 3] + bv.w;
      if (MODE == 0) {
        y.x = (fabsf(y.x) >= 0.05f) ? y.x : 0.0f;
        y.y = (fabsf(y.y) >= 0.05f) ? y.y : 0.0f;
        y.z = (fabsf(y.z) >= 0.05f) ? y.z : 0.0f;
        y.w = (fabsf(y.w) >= 0.05f) ? y.w : 0.0f;
        const int b_ = m >> 11, s_ = m & 2047, h_ = n >> 6, hd_ = n & 63;
        *(float4*)&C[(((size_t)(b_ * HH + h_)) * SS + s_) * HDD + hd_] = y;
      } else {
        *(float4*)&C[(size_t)m * ED + n] = y;
      }
    }
  }
}

// ---------- flash attention fp32, 64x64 tiles ----------
__global__ __launch_bounds__(256) void k_attn(const float* __restrict__ Q,
                                              const float* __restrict__ K,
                                              const float* __restrict__ V,
                                              float* __restrict__ ctx) {
  __shared__ float Qt[64][68];   // [d][q], Q pre-scaled
  __shared__ float KV[64][68];   // K as [d][j], then V as [j][d]
  __shared__ float Pt[64][68];   // [j][q]
  const int t = threadIdx.x, tx = t & 15, ty = t >> 4;
  const int q0 = blockIdx.x * 64;
  const int bh = blockIdx.y;
  const size_t base = (size_t)bh * SS * HDD;

#pragma unroll
  for (int r = 0; r < 4; r++) {
    int i = t + 256 * r;
    int row = i >> 4, dq = i & 15;
    float4 v = *(const float4*)&Q[base + (size_t)(q0 + row) * HDD + dq * 4];
    Qt[dq * 4 + 0][row] = v.x * 0.125f;
    Qt[dq * 4 + 1][row] = v.y * 0.125f;
    Qt[dq * 4 + 2][row] = v.z * 0.125f;
    Qt[dq * 4 + 3][row] = v.w * 0.125f;
  }
  float m[4], l[4] = {0, 0, 0, 0}, o[4][4];
#pragma unroll
  for (int i = 0; i < 4; i++) {
    m[i] = -INFINITY;
#pragma unroll
    for (int j = 0; j < 4; j++) o[i][j] = 0.0f;
  }

  for (int kt = 0; kt < 32; ++kt) {
    const int k0 = kt * 64;
    __syncthreads();  // prev PV done (and Qt visible on first iter)
    // stage K transposed: KV[d][j]
#pragma unroll
    for (int r = 0; r < 4; r++) {
      int i = t + 256 * r;
      int row = i >> 4, dq = i & 15;
      float4 v = *(const float4*)&K[base + (size_t)(k0 + row) * HDD + dq * 4];
      KV[dq * 4 + 0][row] = v.x; KV[dq * 4 + 1][row] = v.y;
      KV[dq * 4 + 2][row] = v.z; KV[dq * 4 + 3][row] = v.w;
    }
    __syncthreads();
    float s[4][4];
#pragma unroll
    for (int i = 0; i < 4; i++)
#pragma unroll
      for (int j = 0; j < 4; j++) s[i][j] = 0.0f;
#pragma unroll 4
    for (int d = 0; d < 64; d++) {
      float4 qv = *(const float4*)&Qt[d][ty * 4];
      float4 kv = *(const float4*)&KV[d][tx * 4];
      float qa[4] = {qv.x, qv.y, qv.z, qv.w};
      float ka[4] = {kv.x, kv.y, kv.z, kv.w};
#pragma unroll
      for (int i = 0; i < 4; i++)
#pragma unroll
        for (int j = 0; j < 4; j++) s[i][j] = fmaf(qa[i], ka[j], s[i][j]);
    }
    // online softmax (rows shared by 16-lane groups)
#pragma unroll
    for (int i = 0; i < 4; i++) {
      float mx = fmaxf(fmaxf(s[i][0], s[i][1]), fmaxf(s[i][2], s[i][3]));
#pragma unroll
      for (int msk = 8; msk; msk >>= 1) mx = fmaxf(mx, __shfl_xor(mx, msk, 64));
      float mnew = fmaxf(m[i], mx);
      float f = expf(m[i] - mnew);
      float sum = 0.0f;
#pragma unroll
      for (int j = 0; j < 4; j++) {
        float p = expf(s[i][j] - mnew);
        s[i][j] = p;
        sum += p;
      }
#pragma unroll
      for (int msk = 8; msk; msk >>= 1) sum += __shfl_xor(sum, msk, 64);
      l[i] = l[i] * f + sum;
      m[i] = mnew;
#pragma unroll
      for (int j = 0; j < 4; j++) o[i][j] *= f;
    }
    // write P transposed [j][q]
#pragma unroll
    for (int i = 0; i < 4; i++)
#pragma unroll
      for (int j = 0; j < 4; j++) Pt[tx * 4 + j][ty * 4 + i] = s[i][j];
    __syncthreads();  // all done reading KV(K); Pt complete
    // stage V natural: KV[j][d]
#pragma unroll
    for (int r = 0; r < 4; r++) {
      int i = t + 256 * r;
      int row = i >> 4, dq = i & 15;
      float4 v = *(const float4*)&V[base + (size_t)(k0 + row) * HDD + dq * 4];
      *(float4*)&KV[row][dq * 4] = v;
    }
    __syncthreads();
    // PV
#pragma unroll 4
    for (int j = 0; j < 64; j++) {
      float4 pv = *(const float4*)&Pt[j][ty * 4];
      float4 vv = *(const float4*)&KV[j][tx * 4];
      float pa[4] = {pv.x, pv.y, pv.z, pv.w};
      float va[4] = {vv.x, vv.y, vv.z, vv.w};
#pragma unroll
      for (int i = 0; i < 4; i++)
#pragma unroll
        for (int jj = 0; jj < 4; jj++) o[i][jj] = fmaf(pa[i], va[jj], o[i][jj]);
    }
  }
  const int b_ = bh >> 4, h_ = bh & 15;
#pragma unroll
  for (int i = 0; i < 4; i++) {
    float inv = 1.0f / l[i];
    float4 y = make_float4(o[i][0] * inv, o[i][1] * inv, o[i][2] * inv, o[i][3] * inv);
    *(float4*)&ctx[((size_t)(b_ * SS + q0 + ty * 4 + i)) * ED + h_ * HDD + tx * 4] = y;
  }
}

extern "C" void kernel_launch(void* const* d_in, const int* in_sizes, int n_in,
                              void* d_out, int out_size, void* d_ws, size_t ws_size,
                              hipStream_t stream) {
  const float* query = (const float*)d_in[0];
  const float* key   = (const float*)d_in[1];
  const float* value = (const float*)d_in[2];
  const float* Wq = (const float*)d_in[3];
  const float* bq = (const float*)d_in[4];
  const float* Wk = (const float*)d_in[5];
  const float* bk = (const float*)d_in[6];
  const float* Wv = (const float*)d_in[7];
  const float* bv = (const float*)d_in[8];
  const float* Wo = (const float*)d_in[9];
  const float* bo = (const float*)d_in[10];
  const float* lng = (const float*)d_in[11];
  const float* lnb = (const float*)d_in[12];
  float* out = (float*)d_out;

  if (ws_size < (size_t)WS_NEEDED) {
    fprintf(stderr, "kernel_launch: ws too small (%zu < %u)\n", ws_size, WS_NEEDED);
    return;
  }

  float* wsf = (float*)d_ws;
  float* weff = wsf;                       // 4 x 1048576
  float* qn  = wsf + 1 * 4194304;
  float* Qb  = wsf + 2 * 4194304;
  float* Kb  = wsf + 3 * 4194304;
  float* Vb  = wsf + 4 * 4194304;
  float* ctx = wsf + 5 * 4194304;
  char* wsb = (char*)d_ws;
  unsigned* histG = (unsigned*)(wsb + HIST_OFF);
  double* pAbs    = (double*)(wsb + PABS_OFF);
  double* pMask   = (double*)(wsb + PMASK_OFF);
  unsigned* pCnt  = (unsigned*)(wsb + PCNT_OFF);
  Stats* st       = (Stats*)(wsb + STATS_OFF);

  hipMemsetAsync(histG, 0, 4096, stream);

  dim3 gW(256, 4);
  k_abs_partial<<<gW, 256, 0, stream>>>(Wq, Wk, Wv, Wo, pAbs);
  k_fin1<<<4, 64, 0, stream>>>(pAbs, st);
  k_masked_partial<<<gW, 256, 0, stream>>>(Wq, Wk, Wv, Wo, st, pMask, pCnt);
  k_fin2<<<4, 64, 0, stream>>>(pMask, pCnt, st);
  for (int pass = 0; pass < 4; ++pass) {
    k_hist<<<gW, 256, 0, stream>>>(Wq, Wk, Wv, Wo, st, histG, pass);
    k_scan<<<4, 256, 0, stream>>>(histG, st, pass);
  }
  k_weff<<<dim3(1024, 4), 256, 0, stream>>>(Wq, Wk, Wv, Wo, st, weff);

  k_ln<<<MROWS, 256, 0, stream>>>(query, lng, lnb, qn);

  k_gemm<0><<<dim3(8, 32), 256, 0, stream>>>(qn, weff + 0 * 1048576, bq, Qb);
  k_gemm<0><<<dim3(8, 32), 256, 0, stream>>>(key, weff + 1 * 1048576, bk, Kb);
  k_gemm<0><<<dim3(8, 32), 256, 0, stream>>>(value, weff + 2 * 1048576, bv, Vb);

  k_attn<<<dim3(32, 32), 256, 0, stream>>>(Qb, Kb, Vb, ctx);

  k_gemm<1><<<dim3(8, 32), 256, 0, stream>>>(ctx, weff + 3 * 1048576, bo, out);
}

// Round 2
// 732.331 us; speedup vs baseline: 1.5434x; 1.5434x over previous
//
#include <hip/hip_runtime.h>
#include <stdio.h>
#include <stdint.h>

// Problem constants
#define BB 2
#define SS 2048
#define ED 1024
#define HH 16
#define HDD 64
#define MROWS 4096            // BB*SS
#define NW_ELEM 1048576u      // ED*ED

typedef unsigned short ushortT;
typedef __attribute__((ext_vector_type(8))) short bf16x8;
typedef __attribute__((ext_vector_type(16))) float f32x16;

// ws layout:
//   floats: weff (4x1M) | qn (4M) | ctx (4M)  = 12M floats = 48MB
//   ushorts after: Qh Ql Kh Kl Vh Vl (each 4M ushort) = 48MB
//   small buffers at byte offset 96MB
#define F_QN    4194304u
#define F_CTX   8388608u
#define U_BASE  12582912u          // float elems before ushort region
#define SMALL_OFF (100663296u)     // 96 MiB
#define HIST_OFF   SMALL_OFF
#define PABS_OFF   (HIST_OFF + 4096u)
#define PMASK_OFF  (PABS_OFF + 8192u)
#define PCNT_OFF   (PMASK_OFF + 8192u)
#define STATS_OFF  (PCNT_OFF + 4096u)
#define WS_NEEDED  (STATS_OFF + 256u)

struct Stats {
  double sumAbs;
  double sumMasked;
  float thr;
  float scale;
  unsigned count;
  unsigned prefix;
  unsigned kcur;
  unsigned pad;
};

__device__ __forceinline__ const float* wsel(int w, const float* W0, const float* W1,
                                             const float* W2, const float* W3) {
  return w == 0 ? W0 : w == 1 ? W1 : w == 2 ? W2 : W3;
}

// bf16 RTNE helpers (bit ops, no header types)
__device__ __forceinline__ ushortT f2bf(float x) {
  unsigned u = __float_as_uint(x);
  unsigned r = (u + 0x7FFFu + ((u >> 16) & 1u)) >> 16;
  return (ushortT)r;
}
__device__ __forceinline__ float bf2f(ushortT b) {
  return __uint_as_float(((unsigned)b) << 16);
}
__device__ __forceinline__ void bsplit(float x, ushortT& h, ushortT& l) {
  ushortT hb = f2bf(x);
  float hf = bf2f(hb);
  h = hb;
  l = f2bf(x - hf);
}

// ---------- pass 1: sum |W| ----------
__global__ __launch_bounds__(256) void k_abs_partial(const float* W0, const float* W1,
                                                     const float* W2, const float* W3,
                                                     double* pAbs) {
  const int w = blockIdx.y, t = threadIdx.x;
  const float* W = wsel(w, W0, W1, W2, W3) + blockIdx.x * 4096;
  double s = 0.0;
#pragma unroll
  for (int r = 0; r < 4; r++) {
    float4 v = *(const float4*)(W + (t + 256 * r) * 4);
    s += (double)fabsf(v.x); s += (double)fabsf(v.y);
    s += (double)fabsf(v.z); s += (double)fabsf(v.w);
  }
  __shared__ double sd[256];
  sd[t] = s;
  __syncthreads();
  for (int off = 128; off > 0; off >>= 1) {
    if (t < off) sd[t] += sd[t + off];
    __syncthreads();
  }
  if (!t) pAbs[w * 256 + blockIdx.x] = sd[0];
}

__global__ void k_fin1(const double* pAbs, Stats* st) {
  const int w = blockIdx.x;
  if (threadIdx.x == 0) {
    double s = 0;
    for (int i = 0; i < 256; i++) s += pAbs[w * 256 + i];
    st[w].sumAbs = s;
    st[w].thr = 0.7f * (float)(s * (1.0 / 1048576.0));
  }
}

// ---------- pass 2: masked sum/count ----------
__global__ __launch_bounds__(256) void k_masked_partial(const float* W0, const float* W1,
                                                        const float* W2, const float* W3,
                                                        const Stats* st, double* pM,
                                                        unsigned* pC) {
  const int w = blockIdx.y, t = threadIdx.x;
  const float thr = st[w].thr;
  const float* W = wsel(w, W0, W1, W2, W3) + blockIdx.x * 4096;
  double s = 0.0;
  unsigned c = 0;
#pragma unroll
  for (int r = 0; r < 4; r++) {
    float4 v = *(const float4*)(W + (t + 256 * r) * 4);
    float xs[4] = {v.x, v.y, v.z, v.w};
#pragma unroll
    for (int q = 0; q < 4; q++) {
      float a = fabsf(xs[q]);
      if (a > thr) { s += (double)a; c++; }
    }
  }
  __shared__ double sd[256];
  __shared__ unsigned sc[256];
  sd[t] = s; sc[t] = c;
  __syncthreads();
  for (int off = 128; off > 0; off >>= 1) {
    if (t < off) { sd[t] += sd[t + off]; sc[t] += sc[t + off]; }
    __syncthreads();
  }
  if (!t) { pM[w * 256 + blockIdx.x] = sd[0]; pC[w * 256 + blockIdx.x] = sc[0]; }
}

__global__ void k_fin2(const double* pM, const unsigned* pC, Stats* st) {
  const int w = blockIdx.x;
  if (threadIdx.x == 0) {
    double s = 0; unsigned c = 0;
    for (int i = 0; i < 256; i++) { s += pM[w * 256 + i]; c += pC[w * 256 + i]; }
    st[w].sumMasked = s;
    st[w].count = c;
    st[w].scale = (float)s / fmaxf((float)c, 1.0f);
  }
}

// ---------- radix select on |res| ----------
__global__ __launch_bounds__(256) void k_hist(const float* W0, const float* W1,
                                              const float* W2, const float* W3,
                                              const Stats* st, unsigned* histG, int pass) {
  const int w = blockIdx.y, t = threadIdx.x;
  __shared__ unsigned h[256];
  h[t] = 0;
  __syncthreads();
  const float thr = st[w].thr, scale = st[w].scale;
  const unsigned prefix = st[w].prefix;
  const float* W = wsel(w, W0, W1, W2, W3) + blockIdx.x * 4096;
#pragma unroll
  for (int r = 0; r < 4; r++) {
    float4 v = *(const float4*)(W + (t + 256 * r) * 4);
    float xs[4] = {v.x, v.y, v.z, v.w};
#pragma unroll
    for (int q = 0; q < 4; q++) {
      float x = xs[q];
      float a = fabsf(x);
      float wq = (a > thr) ? copysignf(scale, x) : 0.0f;
      unsigned bits = __float_as_uint(fabsf(x - wq));
      if (pass == 0) {
        atomicAdd(&h[bits >> 24], 1u);
      } else {
        if ((bits >> (32 - 8 * pass)) == prefix)
          atomicAdd(&h[(bits >> (24 - 8 * pass)) & 255u], 1u);
      }
    }
  }
  __syncthreads();
  if (h[t]) atomicAdd(&histG[w * 256 + t], h[t]);
}

__global__ void k_scan(unsigned* histG, Stats* st, int pass) {
  const int w = blockIdx.x, t = threadIdx.x;
  __shared__ unsigned h[256];
  h[t] = histG[w * 256 + t];
  __syncthreads();
  if (t == 0) {
    unsigned k = (pass == 0) ? ((w == 3) ? 104857u : 52428u) : st[w].kcur;
    unsigned cum = 0;
    int sel = 0;
    for (int b = 255; b >= 0; b--) {
      cum += h[b];
      if (cum >= k) { sel = b; k -= (cum - h[b]); break; }
    }
    unsigned pfx = (pass == 0) ? 0u : st[w].prefix;
    st[w].prefix = (pfx << 8) | (unsigned)sel;
    st[w].kcur = k;
  }
  __syncthreads();
  histG[w * 256 + t] = 0;
}

// ---------- build W_eff ----------
__global__ __launch_bounds__(256) void k_weff(const float* W0, const float* W1,
                                              const float* W2, const float* W3,
                                              const Stats* st, float* weff) {
  const int w = blockIdx.y;
  const unsigned kth = st[w].prefix;
  const float thr = st[w].thr, scale = st[w].scale;
  const unsigned idx = (blockIdx.x * 256 + threadIdx.x) * 4;
  const float* W = wsel(w, W0, W1, W2, W3);
  float4 v = *(const float4*)(W + idx);
  float xs[4] = {v.x, v.y, v.z, v.w};
  float o[4];
#pragma unroll
  for (int c = 0; c < 4; c++) {
    float x = xs[c];
    float a = fabsf(x);
    float wq = (a > thr) ? copysignf(scale, x) : 0.0f;
    float res = x - wq;
    unsigned bits = __float_as_uint(fabsf(res));
    o[c] = wq + ((bits >= kth) ? res : 0.0f);
  }
  float4 ov = make_float4(o[0], o[1], o[2], o[3]);
  *(float4*)(weff + (size_t)w * NW_ELEM + idx) = ov;
}

// ---------- LayerNorm ----------
__global__ __launch_bounds__(256) void k_ln(const float* __restrict__ X,
                                            const float* __restrict__ g,
                                            const float* __restrict__ b,
                                            float* __restrict__ Y) {
  const int row = blockIdx.x, t = threadIdx.x;
  __shared__ float red[8];
  float4 v = *(const float4*)&X[(size_t)row * ED + t * 4];
  float s = v.x + v.y + v.z + v.w;
#pragma unroll
  for (int m = 32; m; m >>= 1) s += __shfl_xor(s, m, 64);
  if ((t & 63) == 0) red[t >> 6] = s;
  __syncthreads();
  float mu = (red[0] + red[1] + red[2] + red[3]) * (1.0f / 1024.0f);
  float dx = v.x - mu, dy = v.y - mu, dz = v.z - mu, dw = v.w - mu;
  float s2 = dx * dx + dy * dy + dz * dz + dw * dw;
#pragma unroll
  for (int m = 32; m; m >>= 1) s2 += __shfl_xor(s2, m, 64);
  if ((t & 63) == 0) red[4 + (t >> 6)] = s2;
  __syncthreads();
  float var = (red[4] + red[5] + red[6] + red[7]) * (1.0f / 1024.0f);
  float inv = rsqrtf(var + 1e-5f);
  float4 gg = *(const float4*)&g[t * 4];
  float4 bb = *(const float4*)&b[t * 4];
  float4 o = make_float4(dx * inv * gg.x + bb.x, dy * inv * gg.y + bb.y,
                         dz * inv * gg.z + bb.z, dw * inv * gg.w + bb.w);
  *(float4*)&Y[(size_t)row * ED + t * 4] = o;
}

// ---------- fp32 GEMM: C = A @ W^T + bias ----------
// MODE 0: route + split -> bf16 hi/lo [B,H,S,HD]
// MODE 1: plain fp32 [M,N]
// MODE 2: route + split -> bf16 hi/lo TRANSPOSED [B,H,HD,S]
template <int MODE>
__global__ __launch_bounds__(256) void k_gemm(const float* __restrict__ A,
                                              const float* __restrict__ Wf,
                                              const float* __restrict__ bias,
                                              void* Cp, void* C2p) {
  __shared__ float As[16][132];
  __shared__ float Bs[16][132];
  const int t = threadIdx.x;
  const int tx = t & 15, ty = t >> 4;
  const int m0 = blockIdx.y * 128, n0 = blockIdx.x * 128;
  float acc[8][8];
#pragma unroll
  for (int i = 0; i < 8; i++)
#pragma unroll
    for (int j = 0; j < 8; j++) acc[i][j] = 0.0f;

  for (int kt = 0; kt < 64; ++kt) {
#pragma unroll
    for (int r = 0; r < 2; r++) {
      int i = t + 256 * r;
      int row = i >> 2, kq = i & 3;
      float4 av = *(const float4*)&A[(size_t)(m0 + row) * ED + kt * 16 + kq * 4];
      float4 bv = *(const float4*)&Wf[(size_t)(n0 + row) * ED + kt * 16 + kq * 4];
      As[kq * 4 + 0][row] = av.x; As[kq * 4 + 1][row] = av.y;
      As[kq * 4 + 2][row] = av.z; As[kq * 4 + 3][row] = av.w;
      Bs[kq * 4 + 0][row] = bv.x; Bs[kq * 4 + 1][row] = bv.y;
      Bs[kq * 4 + 2][row] = bv.z; Bs[kq * 4 + 3][row] = bv.w;
    }
    __syncthreads();
#pragma unroll
    for (int k = 0; k < 16; k++) {
      float4 a0 = *(const float4*)&As[k][ty * 4];
      float4 a1 = *(const float4*)&As[k][ty * 4 + 64];
      float4 b0 = *(const float4*)&Bs[k][tx * 4];
      float4 b1 = *(const float4*)&Bs[k][tx * 4 + 64];
      float a[8] = {a0.x, a0.y, a0.z, a0.w, a1.x, a1.y, a1.z, a1.w};
      float b[8] = {b0.x, b0.y, b0.z, b0.w, b1.x, b1.y, b1.z, b1.w};
#pragma unroll
      for (int i = 0; i < 8; i++)
#pragma unroll
        for (int j = 0; j < 8; j++) acc[i][j] = fmaf(a[i], b[j], acc[i][j]);
    }
    __syncthreads();
  }

  if (MODE == 1) {
    float* C = (float*)Cp;
#pragma unroll
    for (int i = 0; i < 8; i++) {
      const int m = m0 + ty * 4 + (i & 3) + (i >> 2) * 64;
#pragma unroll
      for (int jc = 0; jc < 2; jc++) {
        const int n = n0 + tx * 4 + jc * 64;
        const float4 bv = *(const float4*)&bias[n];
        float4 y;
        y.x = acc[i][jc * 4 + 0] + bv.x;
        y.y = acc[i][jc * 4 + 1] + bv.y;
        y.z = acc[i][jc * 4 + 2] + bv.z;
        y.w = acc[i][jc * 4 + 3] + bv.w;
        *(float4*)&C[(size_t)m * ED + n] = y;
      }
    }
  } else if (MODE == 0) {
    ushortT* Ch = (ushortT*)Cp;
    ushortT* Cl = (ushortT*)C2p;
#pragma unroll
    for (int i = 0; i < 8; i++) {
      const int m = m0 + ty * 4 + (i & 3) + (i >> 2) * 64;
      const int b_ = m >> 11, s_ = m & 2047;
#pragma unroll
      for (int jc = 0; jc < 2; jc++) {
        const int n = n0 + tx * 4 + jc * 64;
        const float4 bv = *(const float4*)&bias[n];
        float ys[4] = {acc[i][jc * 4 + 0] + bv.x, acc[i][jc * 4 + 1] + bv.y,
                       acc[i][jc * 4 + 2] + bv.z, acc[i][jc * 4 + 3] + bv.w};
        ushort4 hv, lv;
        ushortT hh, ll;
#pragma unroll
        for (int c = 0; c < 4; c++) {
          float y = (fabsf(ys[c]) >= 0.05f) ? ys[c] : 0.0f;
          bsplit(y, hh, ll);
          ((ushortT*)&hv)[c] = hh;
          ((ushortT*)&lv)[c] = ll;
        }
        const int h_ = n >> 6, hd_ = n & 63;
        size_t idx = ((size_t)(b_ * HH + h_) * SS + s_) * HDD + hd_;
        *(ushort4*)&Ch[idx] = hv;
        *(ushort4*)&Cl[idx] = lv;
      }
    }
  } else {  // MODE 2: transposed V
    ushortT* Ch = (ushortT*)Cp;
    ushortT* Cl = (ushortT*)C2p;
#pragma unroll
    for (int jc = 0; jc < 2; jc++) {
#pragma unroll
      for (int c = 0; c < 4; c++) {
        const int n = n0 + tx * 4 + jc * 64 + c;
        const int h_ = n >> 6, hd_ = n & 63;
        const float bn = bias[n];
#pragma unroll
        for (int ig = 0; ig < 2; ig++) {
          const int m_ = m0 + ty * 4 + ig * 64;
          const int b_ = m_ >> 11, s_ = m_ & 2047;
          ushort4 hv, lv;
          ushortT hh, ll;
#pragma unroll
          for (int ii = 0; ii < 4; ii++) {
            float y = acc[ig * 4 + ii][jc * 4 + c] + bn;
            y = (fabsf(y) >= 0.05f) ? y : 0.0f;
            bsplit(y, hh, ll);
            ((ushortT*)&hv)[ii] = hh;
            ((ushortT*)&lv)[ii] = ll;
          }
          size_t idx = ((size_t)(b_ * HH + h_) * HDD + hd_) * SS + s_;
          *(ushort4*)&Ch[idx] = hv;
          *(ushort4*)&Cl[idx] = lv;
        }
      }
    }
  }
}

// ---------- MFMA flash attention, split-bf16, 128q-tile, 4 waves x 32q ----------
__device__ __forceinline__ f32x16 mfma32(bf16x8 a, bf16x8 b, f32x16 c) {
  return __builtin_amdgcn_mfma_f32_32x32x16_bf16(a, b, c, 0, 0, 0);
}

__global__ __launch_bounds__(256, 2) void k_attn(
    const ushortT* __restrict__ Qh, const ushortT* __restrict__ Ql,
    const ushortT* __restrict__ Kh, const ushortT* __restrict__ Kl,
    const ushortT* __restrict__ Vh, const ushortT* __restrict__ Vl,
    float* __restrict__ ctx) {
  __shared__ __align__(16) ushortT sKh[4096], sKl[4096];
  __shared__ __align__(16) ushortT sVh[4096], sVl[4096];
  __shared__ __align__(16) ushortT sPh[4096], sPl[4096];

  const int t = threadIdx.x;
  const int w = t >> 6, l = t & 63;
  const int l32 = l & 31, g = l >> 5;

  // XCD-chunked swizzle: each XCD gets 4 consecutive bh (4MB K/V = L2 size)
  int id = blockIdx.x;
  int id2 = (id & 7) * 64 + (id >> 3);
  const int bh = id2 >> 4, qt = id2 & 15;

  const size_t kqbase = (size_t)bh * (SS * HDD);   // [bh][s][64]
  const size_t vbase = (size_t)bh * (HDD * SS);    // [bh][64][s]
  const int q0 = qt * 128 + w * 32;

  // Q fragments in registers (hi/lo), pre-loaded once
  bf16x8 qh[4], ql[4];
  {
    const size_t qrow = kqbase + (size_t)(q0 + l32) * HDD;
#pragma unroll
    for (int ks = 0; ks < 4; ks++) {
      int d0 = ks * 16 + g * 8;
      qh[ks] = *(const bf16x8*)&Qh[qrow + d0];
      ql[ks] = *(const bf16x8*)&Ql[qrow + d0];
    }
  }

  f32x16 octx0, octx1;
  float lsum[16];
#pragma unroll
  for (int i = 0; i < 16; i++) { octx0[i] = 0.0f; octx1[i] = 0.0f; lsum[i] = 0.0f; }

  const float EC = 0.125f * 1.44269504088896f;  // SCALE * log2(e)

  for (int kt = 0; kt < 32; ++kt) {
    const int s0 = kt * 64;
    __syncthreads();
    // stage K and V^T tiles (hi/lo), XOR-swizzled (granule ^= row&7)
#pragma unroll
    for (int r = 0; r < 2; r++) {
      int gi = t + 256 * r;
      int row = gi >> 3, u = gi & 7;
      int lidx = row * 64 + (((u ^ (row & 7))) << 3);
      size_t gK = kqbase + (size_t)(s0 + row) * HDD + u * 8;
      *(uint4*)&sKh[lidx] = *(const uint4*)&Kh[gK];
      *(uint4*)&sKl[lidx] = *(const uint4*)&Kl[gK];
      size_t gV = vbase + (size_t)row * SS + s0 + u * 8;
      *(uint4*)&sVh[lidx] = *(const uint4*)&Vh[gV];
      *(uint4*)&sVl[lidx] = *(const uint4*)&Vl[gV];
    }
    __syncthreads();

    // QK^T: acc[nt] = Q(32xd) . K(kcol= nt*32+l32)
    f32x16 acc0, acc1;
#pragma unroll
    for (int i = 0; i < 16; i++) { acc0[i] = 0.0f; acc1[i] = 0.0f; }
#pragma unroll
    for (int ks = 0; ks < 4; ks++) {
      int u = ks * 2 + g;
      int sw = (u ^ (l32 & 7)) << 3;
      int i0 = l32 * 64 + sw;
      int i1 = (32 + l32) * 64 + sw;
      bf16x8 kh0 = *(const bf16x8*)&sKh[i0];
      bf16x8 kl0 = *(const bf16x8*)&sKl[i0];
      bf16x8 kh1 = *(const bf16x8*)&sKh[i1];
      bf16x8 kl1 = *(const bf16x8*)&sKl[i1];
      acc0 = mfma32(qh[ks], kh0, acc0);
      acc0 = mfma32(qh[ks], kl0, acc0);
      acc0 = mfma32(ql[ks], kh0, acc0);
      acc1 = mfma32(qh[ks], kh1, acc1);
      acc1 = mfma32(qh[ks], kl1, acc1);
      acc1 = mfma32(ql[ks], kh1, acc1);
    }

    // exp (no max subtraction needed: |scores*scale| << 80), P -> LDS, PV
#pragma unroll
    for (int p = 0; p < 2; p++) {
      f32x16& A = p ? acc1 : acc0;
#pragma unroll
      for (int r = 0; r < 16; r++) {
        float pr = exp2f(A[r] * EC);
        lsum[r] += pr;
        int q = (r & 3) + 8 * (r >> 2) + 4 * g;
        int pidx = w * 1024 + q * 32 + ((((l32 >> 3) ^ (q & 3))) << 3) + (l32 & 7);
        ushortT hh, ll;
        bsplit(pr, hh, ll);
        sPh[pidx] = hh;
        sPl[pidx] = ll;
      }
      // wave-local LDS write->read: drain lgkm, keep order
      asm volatile("s_waitcnt lgkmcnt(0)" ::: "memory");
      __builtin_amdgcn_sched_barrier(0);
#pragma unroll
      for (int js = 0; js < 2; js++) {
        int au = ((js * 2 + g) ^ (l32 & 3)) << 3;
        int aidx = w * 1024 + l32 * 32 + au;
        bf16x8 ph = *(const bf16x8*)&sPh[aidx];
        bf16x8 pl = *(const bf16x8*)&sPl[aidx];
        int vu = p * 4 + js * 2 + g;
        int vsw = (vu ^ (l32 & 7)) << 3;
        int vi0 = l32 * 64 + vsw;
        int vi1 = (32 + l32) * 64 + vsw;
        bf16x8 vh0 = *(const bf16x8*)&sVh[vi0];
        bf16x8 vl0 = *(const bf16x8*)&sVl[vi0];
        bf16x8 vh1 = *(const bf16x8*)&sVh[vi1];
        bf16x8 vl1 = *(const bf16x8*)&sVl[vi1];
        octx0 = mfma32(ph, vh0, octx0);
        octx0 = mfma32(ph, vl0, octx0);
        octx0 = mfma32(pl, vh0, octx0);
        octx1 = mfma32(ph, vh1, octx1);
        octx1 = mfma32(ph, vl1, octx1);
        octx1 = mfma32(pl, vh1, octx1);
      }
    }
  }

  // reduce lsum across the 32 lanes sharing g
#pragma unroll
  for (int r = 0; r < 16; r++) {
#pragma unroll
    for (int msk = 16; msk; msk >>= 1) lsum[r] += __shfl_xor(lsum[r], msk, 64);
  }

  const int b_ = bh >> 4, h_ = bh & 15;
#pragma unroll
  for (int r = 0; r < 16; r++) {
    int q = (r & 3) + 8 * (r >> 2) + 4 * g;
    float inv = 1.0f / lsum[r];
    size_t base = ((size_t)(b_ * SS + q0 + q)) * ED + h_ * HDD;
    ctx[base + l32] = octx0[r] * inv;
    ctx[base + 32 + l32] = octx1[r] * inv;
  }
}

extern "C" void kernel_launch(void* const* d_in, const int* in_sizes, int n_in,
                              void* d_out, int out_size, void* d_ws, size_t ws_size,
                              hipStream_t stream) {
  const float* query = (const float*)d_in[0];
  const float* key   = (const float*)d_in[1];
  const float* value = (const float*)d_in[2];
  const float* Wq = (const float*)d_in[3];
  const float* bq = (const float*)d_in[4];
  const float* Wk = (const float*)d_in[5];
  const float* bk = (const float*)d_in[6];
  const float* Wv = (const float*)d_in[7];
  const float* bv = (const float*)d_in[8];
  const float* Wo = (const float*)d_in[9];
  const float* bo = (const float*)d_in[10];
  const float* lng = (const float*)d_in[11];
  const float* lnb = (const float*)d_in[12];
  float* out = (float*)d_out;

  if (ws_size < (size_t)WS_NEEDED) {
    fprintf(stderr, "kernel_launch: ws too small (%zu < %u)\n", ws_size, WS_NEEDED);
    return;
  }

  float* wsf = (float*)d_ws;
  float* weff = wsf;                 // 4 x 1048576 floats
  float* qn   = wsf + F_QN;
  float* ctx  = wsf + F_CTX;
  ushortT* wsu = (ushortT*)(wsf + U_BASE);
  ushortT* Qhp = wsu + 0u * 4194304u;
  ushortT* Qlp = wsu + 1u * 4194304u;
  ushortT* Khp = wsu + 2u * 4194304u;
  ushortT* Klp = wsu + 3u * 4194304u;
  ushortT* Vhp = wsu + 4u * 4194304u;
  ushortT* Vlp = wsu + 5u * 4194304u;

  char* wsb = (char*)d_ws;
  unsigned* histG = (unsigned*)(wsb + HIST_OFF);
  double* pAbs    = (double*)(wsb + PABS_OFF);
  double* pMask   = (double*)(wsb + PMASK_OFF);
  unsigned* pCnt  = (unsigned*)(wsb + PCNT_OFF);
  Stats* st       = (Stats*)(wsb + STATS_OFF);

  hipMemsetAsync(histG, 0, 4096, stream);

  dim3 gW(256, 4);
  k_abs_partial<<<gW, 256, 0, stream>>>(Wq, Wk, Wv, Wo, pAbs);
  k_fin1<<<4, 64, 0, stream>>>(pAbs, st);
  k_masked_partial<<<gW, 256, 0, stream>>>(Wq, Wk, Wv, Wo, st, pMask, pCnt);
  k_fin2<<<4, 64, 0, stream>>>(pMask, pCnt, st);
  for (int pass = 0; pass < 4; ++pass) {
    k_hist<<<gW, 256, 0, stream>>>(Wq, Wk, Wv, Wo, st, histG, pass);
    k_scan<<<4, 256, 0, stream>>>(histG, st, pass);
  }
  k_weff<<<dim3(1024, 4), 256, 0, stream>>>(Wq, Wk, Wv, Wo, st, weff);

  k_ln<<<MROWS, 256, 0, stream>>>(query, lng, lnb, qn);

  k_gemm<0><<<dim3(8, 32), 256, 0, stream>>>(qn, weff + 0 * 1048576, bq, Qhp, Qlp);
  k_gemm<0><<<dim3(8, 32), 256, 0, stream>>>(key, weff + 1 * 1048576, bk, Khp, Klp);
  k_gemm<2><<<dim3(8, 32), 256, 0, stream>>>(value, weff + 2 * 1048576, bv, Vhp, Vlp);

  k_attn<<<512, 256, 0, stream>>>(Qhp, Qlp, Khp, Klp, Vhp, Vlp, ctx);

  k_gemm<1><<<dim3(8, 32), 256, 0, stream>>>(ctx, weff + 3 * 1048576, bo, out, nullptr);
}

// Round 3
// 365.223 us; speedup vs baseline: 3.0948x; 2.0052x over previous
//
#include <hip/hip_runtime.h>
#include <stdio.h>
#include <stdint.h>

// Problem constants
#define BB 2
#define SS 2048
#define ED 1024
#define HH 16
#define HDD 64
#define MROWS 4096            // BB*SS
#define NW_ELEM 1048576u      // ED*ED

typedef unsigned short ushortT;
typedef __attribute__((ext_vector_type(8))) short bf16x8;
typedef __attribute__((ext_vector_type(4))) float f32x4;
typedef __attribute__((ext_vector_type(16))) float f32x16;

// ws layout (ushort elems from base):
//  Whi 0..4M | Wlo 4M..8M | Abuf_h 8M..12M | Abuf_l 12M..16M
//  Qh 16M Ql 20M Kh 24M Kl 28M Vh 32M Vl 36M..40M   (each 4M ushort)
// small buffers at byte offset 80MB
#define U_WHI 0u
#define U_WLO 4194304u
#define U_AH  8388608u
#define U_AL  12582912u
#define U_QH  16777216u
#define U_QL  20971520u
#define U_KH  25165824u
#define U_KL  29360128u
#define U_VH  33554432u
#define U_VL  37748736u
#define SMALL_OFF  83886080u
#define HIST_OFF   SMALL_OFF
#define PABS_OFF   (HIST_OFF + 4096u)
#define PMASK_OFF  (PABS_OFF + 8192u)
#define PCNT_OFF   (PMASK_OFF + 8192u)
#define STATS_OFF  (PCNT_OFF + 4096u)
#define WS_NEEDED  (STATS_OFF + 256u)

struct Stats {
  double sumAbs;
  double sumMasked;
  float thr;
  float scale;
  unsigned count;
  unsigned prefix;
  unsigned kcur;
  unsigned pad;
};

__device__ __forceinline__ const float* wsel(int w, const float* W0, const float* W1,
                                             const float* W2, const float* W3) {
  return w == 0 ? W0 : w == 1 ? W1 : w == 2 ? W2 : W3;
}

// bf16 RTNE helpers
__device__ __forceinline__ ushortT f2bf(float x) {
  unsigned u = __float_as_uint(x);
  unsigned r = (u + 0x7FFFu + ((u >> 16) & 1u)) >> 16;
  return (ushortT)r;
}
__device__ __forceinline__ float bf2f(ushortT b) {
  return __uint_as_float(((unsigned)b) << 16);
}
__device__ __forceinline__ void bsplit(float x, ushortT& h, ushortT& l) {
  ushortT hb = f2bf(x);
  float hf = bf2f(hb);
  h = hb;
  l = f2bf(x - hf);
}

// async global->LDS, 16B/lane; LDS dest wave-uniform base + lane*16
__device__ __forceinline__ void gld_lds16(const ushortT* g, ushortT* s) {
  __builtin_amdgcn_global_load_lds((__attribute__((address_space(1))) void*)g,
                                   (__attribute__((address_space(3))) void*)s, 16, 0, 0);
}

// ---------- pass 1: sum |W| ----------
__global__ __launch_bounds__(256) void k_abs_partial(const float* W0, const float* W1,
                                                     const float* W2, const float* W3,
                                                     double* pAbs) {
  const int w = blockIdx.y, t = threadIdx.x;
  const float* W = wsel(w, W0, W1, W2, W3) + blockIdx.x * 4096;
  double s = 0.0;
#pragma unroll
  for (int r = 0; r < 4; r++) {
    float4 v = *(const float4*)(W + (t + 256 * r) * 4);
    s += (double)fabsf(v.x); s += (double)fabsf(v.y);
    s += (double)fabsf(v.z); s += (double)fabsf(v.w);
  }
  __shared__ double sd[256];
  sd[t] = s;
  __syncthreads();
  for (int off = 128; off > 0; off >>= 1) {
    if (t < off) sd[t] += sd[t + off];
    __syncthreads();
  }
  if (!t) pAbs[w * 256 + blockIdx.x] = sd[0];
}

__global__ void k_fin1(const double* pAbs, Stats* st) {
  const int w = blockIdx.x;
  if (threadIdx.x == 0) {
    double s = 0;
    for (int i = 0; i < 256; i++) s += pAbs[w * 256 + i];
    st[w].sumAbs = s;
    st[w].thr = 0.7f * (float)(s * (1.0 / 1048576.0));
  }
}

// ---------- pass 2: masked sum/count ----------
__global__ __launch_bounds__(256) void k_masked_partial(const float* W0, const float* W1,
                                                        const float* W2, const float* W3,
                                                        const Stats* st, double* pM,
                                                        unsigned* pC) {
  const int w = blockIdx.y, t = threadIdx.x;
  const float thr = st[w].thr;
  const float* W = wsel(w, W0, W1, W2, W3) + blockIdx.x * 4096;
  double s = 0.0;
  unsigned c = 0;
#pragma unroll
  for (int r = 0; r < 4; r++) {
    float4 v = *(const float4*)(W + (t + 256 * r) * 4);
    float xs[4] = {v.x, v.y, v.z, v.w};
#pragma unroll
    for (int q = 0; q < 4; q++) {
      float a = fabsf(xs[q]);
      if (a > thr) { s += (double)a; c++; }
    }
  }
  __shared__ double sd[256];
  __shared__ unsigned sc[256];
  sd[t] = s; sc[t] = c;
  __syncthreads();
  for (int off = 128; off > 0; off >>= 1) {
    if (t < off) { sd[t] += sd[t + off]; sc[t] += sc[t + off]; }
    __syncthreads();
  }
  if (!t) { pM[w * 256 + blockIdx.x] = sd[0]; pC[w * 256 + blockIdx.x] = sc[0]; }
}

__global__ void k_fin2(const double* pM, const unsigned* pC, Stats* st) {
  const int w = blockIdx.x;
  if (threadIdx.x == 0) {
    double s = 0; unsigned c = 0;
    for (int i = 0; i < 256; i++) { s += pM[w * 256 + i]; c += pC[w * 256 + i]; }
    st[w].sumMasked = s;
    st[w].count = c;
    st[w].scale = (float)s / fmaxf((float)c, 1.0f);
  }
}

// ---------- radix select on |res| ----------
__global__ __launch_bounds__(256) void k_hist(const float* W0, const float* W1,
                                              const float* W2, const float* W3,
                                              const Stats* st, unsigned* histG, int pass) {
  const int w = blockIdx.y, t = threadIdx.x;
  __shared__ unsigned h[256];
  h[t] = 0;
  __syncthreads();
  const float thr = st[w].thr, scale = st[w].scale;
  const unsigned prefix = st[w].prefix;
  const float* W = wsel(w, W0, W1, W2, W3) + blockIdx.x * 4096;
#pragma unroll
  for (int r = 0; r < 4; r++) {
    float4 v = *(const float4*)(W + (t + 256 * r) * 4);
    float xs[4] = {v.x, v.y, v.z, v.w};
#pragma unroll
    for (int q = 0; q < 4; q++) {
      float x = xs[q];
      float a = fabsf(x);
      float wq = (a > thr) ? copysignf(scale, x) : 0.0f;
      unsigned bits = __float_as_uint(fabsf(x - wq));
      if (pass == 0) {
        atomicAdd(&h[bits >> 24], 1u);
      } else {
        if ((bits >> (32 - 8 * pass)) == prefix)
          atomicAdd(&h[(bits >> (24 - 8 * pass)) & 255u], 1u);
      }
    }
  }
  __syncthreads();
  if (h[t]) atomicAdd(&histG[w * 256 + t], h[t]);
}

__global__ void k_scan(unsigned* histG, Stats* st, int pass) {
  const int w = blockIdx.x, t = threadIdx.x;
  __shared__ unsigned h[256];
  h[t] = histG[w * 256 + t];
  __syncthreads();
  if (t == 0) {
    unsigned k = (pass == 0) ? ((w == 3) ? 104857u : 52428u) : st[w].kcur;
    unsigned cum = 0;
    int sel = 0;
    for (int b = 255; b >= 0; b--) {
      cum += h[b];
      if (cum >= k) { sel = b; k -= (cum - h[b]); break; }
    }
    unsigned pfx = (pass == 0) ? 0u : st[w].prefix;
    st[w].prefix = (pfx << 8) | (unsigned)sel;
    st[w].kcur = k;
  }
  __syncthreads();
  histG[w * 256 + t] = 0;
}

// ---------- build W_eff, split to bf16 hi/lo ----------
__global__ __launch_bounds__(256) void k_weff(const float* W0, const float* W1,
                                              const float* W2, const float* W3,
                                              const Stats* st, ushortT* Whi, ushortT* Wlo) {
  const int w = blockIdx.y;
  const unsigned kth = st[w].prefix;
  const float thr = st[w].thr, scale = st[w].scale;
  const unsigned idx = (blockIdx.x * 256 + threadIdx.x) * 4;
  const float* W = wsel(w, W0, W1, W2, W3);
  float4 v = *(const float4*)(W + idx);
  float xs[4] = {v.x, v.y, v.z, v.w};
  ushort4 h4, l4;
#pragma unroll
  for (int c = 0; c < 4; c++) {
    float x = xs[c];
    float a = fabsf(x);
    float wq = (a > thr) ? copysignf(scale, x) : 0.0f;
    float res = x - wq;
    unsigned bits = __float_as_uint(fabsf(res));
    float we = wq + ((bits >= kth) ? res : 0.0f);
    ushortT hh, ll;
    bsplit(we, hh, ll);
    ((ushortT*)&h4)[c] = hh;
    ((ushortT*)&l4)[c] = ll;
  }
  *(ushort4*)&Whi[(size_t)w * NW_ELEM + idx] = h4;
  *(ushort4*)&Wlo[(size_t)w * NW_ELEM + idx] = l4;
}

// ---------- LayerNorm -> bf16 hi/lo ----------
__global__ __launch_bounds__(256) void k_ln(const float* __restrict__ X,
                                            const float* __restrict__ g,
                                            const float* __restrict__ b,
                                            ushortT* __restrict__ Yh,
                                            ushortT* __restrict__ Yl) {
  const int row = blockIdx.x, t = threadIdx.x;
  __shared__ float red[8];
  float4 v = *(const float4*)&X[(size_t)row * ED + t * 4];
  float s = v.x + v.y + v.z + v.w;
#pragma unroll
  for (int m = 32; m; m >>= 1) s += __shfl_xor(s, m, 64);
  if ((t & 63) == 0) red[t >> 6] = s;
  __syncthreads();
  float mu = (red[0] + red[1] + red[2] + red[3]) * (1.0f / 1024.0f);
  float dx = v.x - mu, dy = v.y - mu, dz = v.z - mu, dw = v.w - mu;
  float s2 = dx * dx + dy * dy + dz * dz + dw * dw;
#pragma unroll
  for (int m = 32; m; m >>= 1) s2 += __shfl_xor(s2, m, 64);
  if ((t & 63) == 0) red[4 + (t >> 6)] = s2;
  __syncthreads();
  float var = (red[4] + red[5] + red[6] + red[7]) * (1.0f / 1024.0f);
  float inv = rsqrtf(var + 1e-5f);
  float4 gg = *(const float4*)&g[t * 4];
  float4 bb = *(const float4*)&b[t * 4];
  float ys[4] = {dx * inv * gg.x + bb.x, dy * inv * gg.y + bb.y,
                 dz * inv * gg.z + bb.z, dw * inv * gg.w + bb.w};
  ushort4 h4, l4;
#pragma unroll
  for (int c = 0; c < 4; c++) {
    ushortT hh, ll;
    bsplit(ys[c], hh, ll);
    ((ushortT*)&h4)[c] = hh;
    ((ushortT*)&l4)[c] = ll;
  }
  *(ushort4*)&Yh[(size_t)row * ED + t * 4] = h4;
  *(ushort4*)&Yl[(size_t)row * ED + t * 4] = l4;
}

// ---------- fp32 -> bf16 hi/lo split (key/value inputs) ----------
__global__ __launch_bounds__(256) void k_split(const float* __restrict__ X,
                                               ushortT* __restrict__ H,
                                               ushortT* __restrict__ L) {
  const int i = (blockIdx.x * 256 + threadIdx.x) * 4;
  float4 v = *(const float4*)&X[i];
  float xs[4] = {v.x, v.y, v.z, v.w};
  ushort4 h4, l4;
#pragma unroll
  for (int c = 0; c < 4; c++) {
    ushortT hh, ll;
    bsplit(xs[c], hh, ll);
    ((ushortT*)&h4)[c] = hh;
    ((ushortT*)&l4)[c] = ll;
  }
  *(ushort4*)&H[i] = h4;
  *(ushort4*)&L[i] = l4;
}

// ---------- split-bf16 MFMA GEMM: C = A @ W^T + bias ----------
// BM=128 BN=64 BK=64; 4 waves, wave tile 64x32 (4x2 frags of 16x16x32)
// MODE 0: route -> bf16 hi/lo [B,H,S,HD]
// MODE 1: fp32 [M,N]
// MODE 2: route -> bf16 hi/lo transposed [B,H,HD,S]
__device__ __forceinline__ f32x4 mfma16(bf16x8 a, bf16x8 b, f32x4 c) {
  return __builtin_amdgcn_mfma_f32_16x16x32_bf16(a, b, c, 0, 0, 0);
}

template <int MODE>
__global__ __launch_bounds__(256, 2) void k_gemm_mfma(
    const ushortT* __restrict__ Ah, const ushortT* __restrict__ Al,
    const ushortT* __restrict__ Wh, const ushortT* __restrict__ Wl,
    const float* __restrict__ bias, void* Cp, void* C2p) {
  __shared__ __align__(16) ushortT sAh[8192], sAl[8192];  // [128][64]
  __shared__ __align__(16) ushortT sBh[4096], sBl[4096];  // [64][64]
  const int t = threadIdx.x;
  const int w = t >> 6, l = t & 63;
  const int wr = w >> 1, wc = w & 1;

  int id = blockIdx.x;
  int id2 = (id & 7) * 64 + (id >> 3);   // XCD-chunked (512 blocks, bijective)
  const int mt = id2 >> 4, nt = id2 & 15;
  const int m0 = mt * 128, n0 = nt * 64;

  f32x4 acc[4][2];
#pragma unroll
  for (int i = 0; i < 4; i++)
#pragma unroll
    for (int j = 0; j < 2; j++) acc[i][j] = (f32x4){0.0f, 0.0f, 0.0f, 0.0f};

  const int sr = l >> 3, sg = l & 7;
  const int swz = sg ^ sr;               // staging source-granule swizzle

  for (int kt = 0; kt < 16; ++kt) {
    __syncthreads();
    // stage tiles (pre-swizzled global source, linear LDS dest)
#pragma unroll
    for (int s2 = 0; s2 < 4; s2++) {
      int seg = w * 4 + s2;
      size_t g = (size_t)(m0 + seg * 8 + sr) * ED + kt * 64 + swz * 8;
      gld_lds16(Ah + g, sAh + seg * 512);
      gld_lds16(Al + g, sAl + seg * 512);
    }
#pragma unroll
    for (int s2 = 0; s2 < 2; s2++) {
      int seg = w * 2 + s2;
      size_t g = (size_t)(n0 + seg * 8 + sr) * ED + kt * 64 + swz * 8;
      gld_lds16(Wh + g, sBh + seg * 512);
      gld_lds16(Wl + g, sBl + seg * 512);
    }
    __syncthreads();
#pragma unroll
    for (int ks = 0; ks < 2; ks++) {
      bf16x8 ah[4], al[4], bh[2], bl[2];
      const int G = ks * 4 + (l >> 4);
#pragma unroll
      for (int i = 0; i < 4; i++) {
        int r = wr * 64 + i * 16 + (l & 15);
        int off = r * 64 + ((G ^ (l & 7)) << 3);
        ah[i] = *(const bf16x8*)&sAh[off];
        al[i] = *(const bf16x8*)&sAl[off];
      }
#pragma unroll
      for (int j = 0; j < 2; j++) {
        int r = wc * 32 + j * 16 + (l & 15);
        int off = r * 64 + ((G ^ (l & 7)) << 3);
        bh[j] = *(const bf16x8*)&sBh[off];
        bl[j] = *(const bf16x8*)&sBl[off];
      }
#pragma unroll
      for (int i = 0; i < 4; i++)
#pragma unroll
        for (int j = 0; j < 2; j++) {
          acc[i][j] = mfma16(ah[i], bh[j], acc[i][j]);
          acc[i][j] = mfma16(ah[i], bl[j], acc[i][j]);
          acc[i][j] = mfma16(al[i], bh[j], acc[i][j]);
        }
    }
  }

  // epilogue: D layout col = l&15, row = (l>>4)*4 + reg
  const int coln = l & 15, row4 = (l >> 4) * 4;
  float bn[2];
#pragma unroll
  for (int j = 0; j < 2; j++) bn[j] = bias[n0 + wc * 32 + j * 16 + coln];

  if (MODE == 1) {
    float* C = (float*)Cp;
#pragma unroll
    for (int i = 0; i < 4; i++)
#pragma unroll
      for (int j = 0; j < 2; j++) {
        int n = n0 + wc * 32 + j * 16 + coln;
#pragma unroll
        for (int r = 0; r < 4; r++) {
          int m = m0 + wr * 64 + i * 16 + row4 + r;
          C[(size_t)m * ED + n] = acc[i][j][r] + bn[j];
        }
      }
  } else if (MODE == 0) {
    ushortT* Ch = (ushortT*)Cp;
    ushortT* Cl = (ushortT*)C2p;
    const int b_ = m0 >> 11, h_ = n0 >> 6;
#pragma unroll
    for (int i = 0; i < 4; i++)
#pragma unroll
      for (int j = 0; j < 2; j++) {
        int hd = wc * 32 + j * 16 + coln;
#pragma unroll
        for (int r = 0; r < 4; r++) {
          int m = m0 + wr * 64 + i * 16 + row4 + r;
          int s_ = m & 2047;
          float y = acc[i][j][r] + bn[j];
          y = (fabsf(y) >= 0.05f) ? y : 0.0f;
          ushortT hh, ll;
          bsplit(y, hh, ll);
          size_t idx = ((size_t)(b_ * HH + h_) * SS + s_) * HDD + hd;
          Ch[idx] = hh;
          Cl[idx] = ll;
        }
      }
  } else {  // MODE 2: transposed V [B,H,HD,S]
    ushortT* Ch = (ushortT*)Cp;
    ushortT* Cl = (ushortT*)C2p;
    const int b_ = m0 >> 11, h_ = n0 >> 6;
#pragma unroll
    for (int i = 0; i < 4; i++)
#pragma unroll
      for (int j = 0; j < 2; j++) {
        int hd = wc * 32 + j * 16 + coln;
        int s0_ = (m0 + wr * 64 + i * 16 + row4) & 2047;
        ushort4 h4, l4;
#pragma unroll
        for (int r = 0; r < 4; r++) {
          float y = acc[i][j][r] + bn[j];
          y = (fabsf(y) >= 0.05f) ? y : 0.0f;
          ushortT hh, ll;
          bsplit(y, hh, ll);
          ((ushortT*)&h4)[r] = hh;
          ((ushortT*)&l4)[r] = ll;
        }
        size_t idx = ((size_t)(b_ * HH + h_) * HDD + hd) * SS + s0_;
        *(ushort4*)&Ch[idx] = h4;
        *(ushort4*)&Cl[idx] = l4;
      }
  }
}

// ---------- MFMA flash attention, split-bf16 (unchanged core from R2) ----------
__device__ __forceinline__ f32x16 mfma32(bf16x8 a, bf16x8 b, f32x16 c) {
  return __builtin_amdgcn_mfma_f32_32x32x16_bf16(a, b, c, 0, 0, 0);
}

__global__ __launch_bounds__(256, 2) void k_attn(
    const ushortT* __restrict__ Qh, const ushortT* __restrict__ Ql,
    const ushortT* __restrict__ Kh, const ushortT* __restrict__ Kl,
    const ushortT* __restrict__ Vh, const ushortT* __restrict__ Vl,
    ushortT* __restrict__ ctxH, ushortT* __restrict__ ctxL) {
  __shared__ __align__(16) ushortT sKh[4096], sKl[4096];
  __shared__ __align__(16) ushortT sVh[4096], sVl[4096];
  __shared__ __align__(16) ushortT sPh[4096], sPl[4096];

  const int t = threadIdx.x;
  const int w = t >> 6, l = t & 63;
  const int l32 = l & 31, g = l >> 5;

  int id = blockIdx.x;
  int id2 = (id & 7) * 64 + (id >> 3);
  const int bh = id2 >> 4, qt = id2 & 15;

  const size_t kqbase = (size_t)bh * (SS * HDD);
  const size_t vbase = (size_t)bh * (HDD * SS);
  const int q0 = qt * 128 + w * 32;

  bf16x8 qh[4], ql[4];
  {
    const size_t qrow = kqbase + (size_t)(q0 + l32) * HDD;
#pragma unroll
    for (int ks = 0; ks < 4; ks++) {
      int d0 = ks * 16 + g * 8;
      qh[ks] = *(const bf16x8*)&Qh[qrow + d0];
      ql[ks] = *(const bf16x8*)&Ql[qrow + d0];
    }
  }

  f32x16 octx0, octx1;
  float lsum[16];
#pragma unroll
  for (int i = 0; i < 16; i++) { octx0[i] = 0.0f; octx1[i] = 0.0f; lsum[i] = 0.0f; }

  const float EC = 0.125f * 1.44269504088896f;

  for (int kt = 0; kt < 32; ++kt) {
    const int s0 = kt * 64;
    __syncthreads();
#pragma unroll
    for (int r = 0; r < 2; r++) {
      int gi = t + 256 * r;
      int row = gi >> 3, u = gi & 7;
      int lidx = row * 64 + (((u ^ (row & 7))) << 3);
      size_t gK = kqbase + (size_t)(s0 + row) * HDD + u * 8;
      *(uint4*)&sKh[lidx] = *(const uint4*)&Kh[gK];
      *(uint4*)&sKl[lidx] = *(const uint4*)&Kl[gK];
      size_t gV = vbase + (size_t)row * SS + s0 + u * 8;
      *(uint4*)&sVh[lidx] = *(const uint4*)&Vh[gV];
      *(uint4*)&sVl[lidx] = *(const uint4*)&Vl[gV];
    }
    __syncthreads();

    f32x16 acc0, acc1;
#pragma unroll
    for (int i = 0; i < 16; i++) { acc0[i] = 0.0f; acc1[i] = 0.0f; }
#pragma unroll
    for (int ks = 0; ks < 4; ks++) {
      int u = ks * 2 + g;
      int sw = (u ^ (l32 & 7)) << 3;
      int i0 = l32 * 64 + sw;
      int i1 = (32 + l32) * 64 + sw;
      bf16x8 kh0 = *(const bf16x8*)&sKh[i0];
      bf16x8 kl0 = *(const bf16x8*)&sKl[i0];
      bf16x8 kh1 = *(const bf16x8*)&sKh[i1];
      bf16x8 kl1 = *(const bf16x8*)&sKl[i1];
      acc0 = mfma32(qh[ks], kh0, acc0);
      acc0 = mfma32(qh[ks], kl0, acc0);
      acc0 = mfma32(ql[ks], kh0, acc0);
      acc1 = mfma32(qh[ks], kh1, acc1);
      acc1 = mfma32(qh[ks], kl1, acc1);
      acc1 = mfma32(ql[ks], kh1, acc1);
    }

#pragma unroll
    for (int p = 0; p < 2; p++) {
      f32x16& A = p ? acc1 : acc0;
#pragma unroll
      for (int r = 0; r < 16; r++) {
        float pr = exp2f(A[r] * EC);
        lsum[r] += pr;
        int q = (r & 3) + 8 * (r >> 2) + 4 * g;
        int pidx = w * 1024 + q * 32 + ((((l32 >> 3) ^ (q & 3))) << 3) + (l32 & 7);
        ushortT hh, ll;
        bsplit(pr, hh, ll);
        sPh[pidx] = hh;
        sPl[pidx] = ll;
      }
      asm volatile("s_waitcnt lgkmcnt(0)" ::: "memory");
      __builtin_amdgcn_sched_barrier(0);
#pragma unroll
      for (int js = 0; js < 2; js++) {
        int au = ((js * 2 + g) ^ (l32 & 3)) << 3;
        int aidx = w * 1024 + l32 * 32 + au;
        bf16x8 ph = *(const bf16x8*)&sPh[aidx];
        bf16x8 pl = *(const bf16x8*)&sPl[aidx];
        int vu = p * 4 + js * 2 + g;
        int vsw = (vu ^ (l32 & 7)) << 3;
        int vi0 = l32 * 64 + vsw;
        int vi1 = (32 + l32) * 64 + vsw;
        bf16x8 vh0 = *(const bf16x8*)&sVh[vi0];
        bf16x8 vl0 = *(const bf16x8*)&sVl[vi0];
        bf16x8 vh1 = *(const bf16x8*)&sVh[vi1];
        bf16x8 vl1 = *(const bf16x8*)&sVl[vi1];
        octx0 = mfma32(ph, vh0, octx0);
        octx0 = mfma32(ph, vl0, octx0);
        octx0 = mfma32(pl, vh0, octx0);
        octx1 = mfma32(ph, vh1, octx1);
        octx1 = mfma32(ph, vl1, octx1);
        octx1 = mfma32(pl, vh1, octx1);
      }
    }
  }

#pragma unroll
  for (int r = 0; r < 16; r++) {
#pragma unroll
    for (int msk = 16; msk; msk >>= 1) lsum[r] += __shfl_xor(lsum[r], msk, 64);
  }

  const int b_ = bh >> 4, h_ = bh & 15;
#pragma unroll
  for (int r = 0; r < 16; r++) {
    int q = (r & 3) + 8 * (r >> 2) + 4 * g;
    float inv = 1.0f / lsum[r];
    size_t base = ((size_t)(b_ * SS + q0 + q)) * ED + h_ * HDD;
    ushortT hh, ll;
    bsplit(octx0[r] * inv, hh, ll);
    ctxH[base + l32] = hh;
    ctxL[base + l32] = ll;
    bsplit(octx1[r] * inv, hh, ll);
    ctxH[base + 32 + l32] = hh;
    ctxL[base + 32 + l32] = ll;
  }
}

extern "C" void kernel_launch(void* const* d_in, const int* in_sizes, int n_in,
                              void* d_out, int out_size, void* d_ws, size_t ws_size,
                              hipStream_t stream) {
  const float* query = (const float*)d_in[0];
  const float* key   = (const float*)d_in[1];
  const float* value = (const float*)d_in[2];
  const float* Wq = (const float*)d_in[3];
  const float* bq = (const float*)d_in[4];
  const float* Wk = (const float*)d_in[5];
  const float* bk = (const float*)d_in[6];
  const float* Wv = (const float*)d_in[7];
  const float* bv = (const float*)d_in[8];
  const float* Wo = (const float*)d_in[9];
  const float* bo = (const float*)d_in[10];
  const float* lng = (const float*)d_in[11];
  const float* lnb = (const float*)d_in[12];
  float* out = (float*)d_out;

  if (ws_size < (size_t)WS_NEEDED) {
    fprintf(stderr, "kernel_launch: ws too small (%zu < %u)\n", ws_size, WS_NEEDED);
    return;
  }

  ushortT* wsu = (ushortT*)d_ws;
  ushortT* Whi = wsu + U_WHI;
  ushortT* Wlo = wsu + U_WLO;
  ushortT* Abh = wsu + U_AH;
  ushortT* Abl = wsu + U_AL;
  ushortT* Qhp = wsu + U_QH;
  ushortT* Qlp = wsu + U_QL;
  ushortT* Khp = wsu + U_KH;
  ushortT* Klp = wsu + U_KL;
  ushortT* Vhp = wsu + U_VH;
  ushortT* Vlp = wsu + U_VL;

  char* wsb = (char*)d_ws;
  unsigned* histG = (unsigned*)(wsb + HIST_OFF);
  double* pAbs    = (double*)(wsb + PABS_OFF);
  double* pMask   = (double*)(wsb + PMASK_OFF);
  unsigned* pCnt  = (unsigned*)(wsb + PCNT_OFF);
  Stats* st       = (Stats*)(wsb + STATS_OFF);

  hipMemsetAsync(histG, 0, 4096, stream);

  dim3 gW(256, 4);
  k_abs_partial<<<gW, 256, 0, stream>>>(Wq, Wk, Wv, Wo, pAbs);
  k_fin1<<<4, 64, 0, stream>>>(pAbs, st);
  k_masked_partial<<<gW, 256, 0, stream>>>(Wq, Wk, Wv, Wo, st, pMask, pCnt);
  k_fin2<<<4, 64, 0, stream>>>(pMask, pCnt, st);
  for (int pass = 0; pass < 4; ++pass) {
    k_hist<<<gW, 256, 0, stream>>>(Wq, Wk, Wv, Wo, st, histG, pass);
    k_scan<<<4, 256, 0, stream>>>(histG, st, pass);
  }
  k_weff<<<dim3(1024, 4), 256, 0, stream>>>(Wq, Wk, Wv, Wo, st, Whi, Wlo);

  // q path: LN -> Abuf; GEMM -> Q
  k_ln<<<MROWS, 256, 0, stream>>>(query, lng, lnb, Abh, Abl);
  k_gemm_mfma<0><<<512, 256, 0, stream>>>(Abh, Abl, Whi + 0 * NW_ELEM, Wlo + 0 * NW_ELEM,
                                          bq, Qhp, Qlp);
  // k path
  k_split<<<4096, 256, 0, stream>>>(key, Abh, Abl);
  k_gemm_mfma<0><<<512, 256, 0, stream>>>(Abh, Abl, Whi + 1 * NW_ELEM, Wlo + 1 * NW_ELEM,
                                          bk, Khp, Klp);
  // v path (transposed output)
  k_split<<<4096, 256, 0, stream>>>(value, Abh, Abl);
  k_gemm_mfma<2><<<512, 256, 0, stream>>>(Abh, Abl, Whi + 2 * NW_ELEM, Wlo + 2 * NW_ELEM,
                                          bv, Vhp, Vlp);

  // attention -> ctx (into Abuf)
  k_attn<<<512, 256, 0, stream>>>(Qhp, Qlp, Khp, Klp, Vhp, Vlp, Abh, Abl);

  // out projection
  k_gemm_mfma<1><<<512, 256, 0, stream>>>(Abh, Abl, Whi + 3 * NW_ELEM, Wlo + 3 * NW_ELEM,
                                          bo, out, nullptr);
}

// Round 4
// 293.566 us; speedup vs baseline: 3.8502x; 1.2441x over previous
//
#include <hip/hip_runtime.h>
#include <stdio.h>
#include <stdint.h>

// Problem constants
#define BB 2
#define SS 2048
#define ED 1024
#define HH 16
#define HDD 64
#define MROWS 4096            // BB*SS
#define NW_ELEM 1048576u      // ED*ED

typedef unsigned short ushortT;
typedef __attribute__((ext_vector_type(8))) short bf16x8;
typedef __attribute__((ext_vector_type(4))) float f32x4;
typedef __attribute__((ext_vector_type(16))) float f32x16;

// ws layout (ushort elems from base):
#define U_WHI 0u
#define U_WLO 4194304u
#define U_AH  8388608u
#define U_AL  12582912u
#define U_BH  16777216u
#define U_BL  20971520u
#define U_QH  25165824u
#define U_QL  29360128u
#define U_KH  33554432u
#define U_KL  37748736u
#define U_VH  41943040u
#define U_VL  46137344u
// byte offsets for small buffers (after 96MB of ushort regions)
#define SMALL_OFF  100663296u
#define HIST_OFF   SMALL_OFF                 // 4 passes * 4 w * 256 bins * 4B = 16384
#define ABS_OFF    (SMALL_OFF + 16384u)      // 4 * 8B
#define MSK_OFF    (ABS_OFF + 32u)           // 4 * 8B
#define CNT_OFF    (MSK_OFF + 32u)           // 4 * 4B
#define SMALL_BYTES 16464u
#define WS_NEEDED  (SMALL_OFF + SMALL_BYTES)

#define SC44 17592186044416.0f               // 2^44
#define INV44 (1.0 / 17592186044416.0)

__device__ __forceinline__ const float* wsel(int w, const float* W0, const float* W1,
                                             const float* W2, const float* W3) {
  return w == 0 ? W0 : w == 1 ? W1 : w == 2 ? W2 : W3;
}

// bf16 RTNE helpers
__device__ __forceinline__ ushortT f2bf(float x) {
  unsigned u = __float_as_uint(x);
  unsigned r = (u + 0x7FFFu + ((u >> 16) & 1u)) >> 16;
  return (ushortT)r;
}
__device__ __forceinline__ float bf2f(ushortT b) {
  return __uint_as_float(((unsigned)b) << 16);
}
__device__ __forceinline__ void bsplit(float x, ushortT& h, ushortT& l) {
  ushortT hb = f2bf(x);
  float hf = bf2f(hb);
  h = hb;
  l = f2bf(x - hf);
}
// packed bf16 convert (RTNE) and cross-row swap
__device__ __forceinline__ unsigned pkbf(float a, float b) {
  unsigned r;
  asm("v_cvt_pk_bf16_f32 %0, %1, %2" : "=v"(r) : "v"(a), "v"(b));
  return r;
}
__device__ __forceinline__ void plswap(unsigned& a, unsigned& b) {
  asm("v_permlane32_swap_b32 %0, %1" : "+v"(a), "+v"(b));
}

// async global->LDS, 16B/lane; LDS dest = wave-uniform base + lane*16
__device__ __forceinline__ void gld_lds16(const ushortT* g, ushortT* s) {
  __builtin_amdgcn_global_load_lds((__attribute__((address_space(1))) void*)g,
                                   (__attribute__((address_space(3))) void*)s, 16, 0, 0);
}

__device__ __forceinline__ float get_thr(const unsigned long long* sAbs, int w) {
  return 0.7f * (float)((double)sAbs[w] * INV44 / 1048576.0);
}
__device__ __forceinline__ float get_scale(const unsigned long long* sMsk,
                                           const unsigned* cnt, int w) {
  double s = (double)sMsk[w] * INV44;
  return (float)s / fmaxf((float)cnt[w], 1.0f);
}

// parallel radix-select step: suffix-scan hist, pick bucket, update (k, prefix)
__device__ __forceinline__ void scan_sel(const unsigned* hist, unsigned& k, unsigned& prefix,
                                         unsigned* sh, int t) {
  sh[t] = hist[t];
  __syncthreads();
  for (int off = 1; off < 256; off <<= 1) {
    unsigned add = (t + off < 256) ? sh[t + off] : 0u;
    __syncthreads();
    sh[t] += add;
    __syncthreads();
  }
  int sel = __syncthreads_count((int)(sh[t] >= k)) - 1;
  unsigned suf = sh[sel];
  k -= (suf - hist[sel]);
  prefix = (prefix << 8) | (unsigned)sel;
  __syncthreads();
}

// ---------- pass 1: sum |W| (integer fixed-point atomics, deterministic) ----------
__global__ __launch_bounds__(256) void k_wstats(const float* W0, const float* W1,
                                                const float* W2, const float* W3,
                                                unsigned long long* sAbs) {
  const int w = blockIdx.y, t = threadIdx.x;
  const float* W = wsel(w, W0, W1, W2, W3) + blockIdx.x * 4096;
  unsigned long long s = 0;
#pragma unroll
  for (int r = 0; r < 4; r++) {
    float4 v = *(const float4*)(W + (t + 256 * r) * 4);
    s += (unsigned long long)(fabsf(v.x) * SC44);
    s += (unsigned long long)(fabsf(v.y) * SC44);
    s += (unsigned long long)(fabsf(v.z) * SC44);
    s += (unsigned long long)(fabsf(v.w) * SC44);
  }
  __shared__ unsigned long long sd[256];
  sd[t] = s;
  __syncthreads();
  for (int off = 128; off > 0; off >>= 1) {
    if (t < off) sd[t] += sd[t + off];
    __syncthreads();
  }
  if (!t) atomicAdd(&sAbs[w], sd[0]);
}

// ---------- pass 2: masked sum/count ----------
__global__ __launch_bounds__(256) void k_masked(const float* W0, const float* W1,
                                                const float* W2, const float* W3,
                                                const unsigned long long* sAbs,
                                                unsigned long long* sMsk, unsigned* sCnt) {
  const int w = blockIdx.y, t = threadIdx.x;
  const float thr = get_thr(sAbs, w);
  const float* W = wsel(w, W0, W1, W2, W3) + blockIdx.x * 4096;
  unsigned long long s = 0;
  unsigned c = 0;
#pragma unroll
  for (int r = 0; r < 4; r++) {
    float4 v = *(const float4*)(W + (t + 256 * r) * 4);
    float xs[4] = {v.x, v.y, v.z, v.w};
#pragma unroll
    for (int q = 0; q < 4; q++) {
      float a = fabsf(xs[q]);
      if (a > thr) { s += (unsigned long long)(a * SC44); c++; }
    }
  }
  __shared__ unsigned long long sd[256];
  __shared__ unsigned sc[256];
  sd[t] = s; sc[t] = c;
  __syncthreads();
  for (int off = 128; off > 0; off >>= 1) {
    if (t < off) { sd[t] += sd[t + off]; sc[t] += sc[t + off]; }
    __syncthreads();
  }
  if (!t) { atomicAdd(&sMsk[w], sd[0]); atomicAdd(&sCnt[w], sc[0]); }
}

// ---------- radix histogram pass (prologue recomputes prefix chain) ----------
__global__ __launch_bounds__(256) void k_hist(const float* W0, const float* W1,
                                              const float* W2, const float* W3,
                                              const unsigned long long* sAbs,
                                              const unsigned long long* sMsk,
                                              const unsigned* sCnt,
                                              unsigned* histG, int pass) {
  const int w = blockIdx.y, t = threadIdx.x;
  __shared__ unsigned sh[256];
  __shared__ unsigned h[256];
  const float thr = get_thr(sAbs, w);
  const float scale = get_scale(sMsk, sCnt, w);
  unsigned k = (w == 3) ? 104857u : 52428u, prefix = 0u;
  for (int pp = 0; pp < pass; pp++)
    scan_sel(histG + (pp * 4 + w) * 256, k, prefix, sh, t);

  h[t] = 0;
  __syncthreads();
  const float* W = wsel(w, W0, W1, W2, W3) + blockIdx.x * 4096;
  const int shift1 = 32 - 8 * pass;
  const int shift2 = 24 - 8 * pass;
#pragma unroll
  for (int r = 0; r < 4; r++) {
    float4 v = *(const float4*)(W + (t + 256 * r) * 4);
    float xs[4] = {v.x, v.y, v.z, v.w};
#pragma unroll
    for (int q = 0; q < 4; q++) {
      float x = xs[q];
      float a = fabsf(x);
      float wq = (a > thr) ? copysignf(scale, x) : 0.0f;
      unsigned bits = __float_as_uint(fabsf(x - wq));
      if (pass == 0) {
        atomicAdd(&h[bits >> 24], 1u);
      } else {
        if ((bits >> shift1) == prefix)
          atomicAdd(&h[(bits >> shift2) & 255u], 1u);
      }
    }
  }
  __syncthreads();
  if (h[t]) atomicAdd(&histG[(pass * 4 + w) * 256 + t], h[t]);
}

// ---------- build W_eff, split to bf16 hi/lo (prologue: full chain -> kth) ----------
__global__ __launch_bounds__(256) void k_weff(const float* W0, const float* W1,
                                              const float* W2, const float* W3,
                                              const unsigned long long* sAbs,
                                              const unsigned long long* sMsk,
                                              const unsigned* sCnt,
                                              const unsigned* histG,
                                              ushortT* Whi, ushortT* Wlo) {
  const int w = blockIdx.y, t = threadIdx.x;
  __shared__ unsigned sh[256];
  const float thr = get_thr(sAbs, w);
  const float scale = get_scale(sMsk, sCnt, w);
  unsigned k = (w == 3) ? 104857u : 52428u, kth = 0u;
  for (int pp = 0; pp < 4; pp++)
    scan_sel(histG + (pp * 4 + w) * 256, k, kth, sh, t);

  const unsigned idx = (blockIdx.x * 256 + t) * 4;
  const float* W = wsel(w, W0, W1, W2, W3);
  float4 v = *(const float4*)(W + idx);
  float xs[4] = {v.x, v.y, v.z, v.w};
  ushort4 h4, l4;
#pragma unroll
  for (int c = 0; c < 4; c++) {
    float x = xs[c];
    float a = fabsf(x);
    float wq = (a > thr) ? copysignf(scale, x) : 0.0f;
    float res = x - wq;
    unsigned bits = __float_as_uint(fabsf(res));
    float we = wq + ((bits >= kth) ? res : 0.0f);
    ushortT hh, ll;
    bsplit(we, hh, ll);
    ((ushortT*)&h4)[c] = hh;
    ((ushortT*)&l4)[c] = ll;
  }
  *(ushort4*)&Whi[(size_t)w * NW_ELEM + idx] = h4;
  *(ushort4*)&Wlo[(size_t)w * NW_ELEM + idx] = l4;
}

// ---------- fused: y0 = LayerNorm(query) -> A ; y1 = split(key) -> B ----------
__global__ __launch_bounds__(256) void k_pre(const float* __restrict__ query,
                                             const float* __restrict__ key,
                                             const float* __restrict__ g,
                                             const float* __restrict__ b,
                                             ushortT* __restrict__ Ah, ushortT* __restrict__ Al,
                                             ushortT* __restrict__ Bh, ushortT* __restrict__ Bl) {
  const int t = threadIdx.x;
  if (blockIdx.y == 0) {
    const int row = blockIdx.x;
    __shared__ float red[8];
    float4 v = *(const float4*)&query[(size_t)row * ED + t * 4];
    float s = v.x + v.y + v.z + v.w;
#pragma unroll
    for (int m = 32; m; m >>= 1) s += __shfl_xor(s, m, 64);
    if ((t & 63) == 0) red[t >> 6] = s;
    __syncthreads();
    float mu = (red[0] + red[1] + red[2] + red[3]) * (1.0f / 1024.0f);
    float dx = v.x - mu, dy = v.y - mu, dz = v.z - mu, dw = v.w - mu;
    float s2 = dx * dx + dy * dy + dz * dz + dw * dw;
#pragma unroll
    for (int m = 32; m; m >>= 1) s2 += __shfl_xor(s2, m, 64);
    if ((t & 63) == 0) red[4 + (t >> 6)] = s2;
    __syncthreads();
    float var = (red[4] + red[5] + red[6] + red[7]) * (1.0f / 1024.0f);
    float inv = rsqrtf(var + 1e-5f);
    float4 gg = *(const float4*)&g[t * 4];
    float4 bb = *(const float4*)&b[t * 4];
    float ys[4] = {dx * inv * gg.x + bb.x, dy * inv * gg.y + bb.y,
                   dz * inv * gg.z + bb.z, dw * inv * gg.w + bb.w};
    ushort4 h4, l4;
#pragma unroll
    for (int c = 0; c < 4; c++) {
      ushortT hh, ll;
      bsplit(ys[c], hh, ll);
      ((ushortT*)&h4)[c] = hh;
      ((ushortT*)&l4)[c] = ll;
    }
    *(ushort4*)&Ah[(size_t)row * ED + t * 4] = h4;
    *(ushort4*)&Al[(size_t)row * ED + t * 4] = l4;
  } else {
    const int i = (blockIdx.x * 256 + t) * 4;
    float4 v = *(const float4*)&key[i];
    float xs[4] = {v.x, v.y, v.z, v.w};
    ushort4 h4, l4;
#pragma unroll
    for (int c = 0; c < 4; c++) {
      ushortT hh, ll;
      bsplit(xs[c], hh, ll);
      ((ushortT*)&h4)[c] = hh;
      ((ushortT*)&l4)[c] = ll;
    }
    *(ushort4*)&Bh[i] = h4;
    *(ushort4*)&Bl[i] = l4;
  }
}

// ---------- fp32 -> bf16 hi/lo split (value) ----------
__global__ __launch_bounds__(256) void k_splitv(const float* __restrict__ X,
                                                ushortT* __restrict__ H,
                                                ushortT* __restrict__ L) {
  const int i = (blockIdx.x * 256 + threadIdx.x) * 4;
  float4 v = *(const float4*)&X[i];
  float xs[4] = {v.x, v.y, v.z, v.w};
  ushort4 h4, l4;
#pragma unroll
  for (int c = 0; c < 4; c++) {
    ushortT hh, ll;
    bsplit(xs[c], hh, ll);
    ((ushortT*)&h4)[c] = hh;
    ((ushortT*)&l4)[c] = ll;
  }
  *(ushort4*)&H[i] = h4;
  *(ushort4*)&L[i] = l4;
}

// ---------- split-bf16 MFMA GEMM: C = A @ W^T + bias ----------
__device__ __forceinline__ f32x4 mfma16(bf16x8 a, bf16x8 b, f32x4 c) {
  return __builtin_amdgcn_mfma_f32_16x16x32_bf16(a, b, c, 0, 0, 0);
}

template <int MODE>
__global__ __launch_bounds__(256, 2) void k_gemm_mfma(
    const ushortT* __restrict__ Ah, const ushortT* __restrict__ Al,
    const ushortT* __restrict__ Wh, const ushortT* __restrict__ Wl,
    const float* __restrict__ bias, void* Cp, void* C2p) {
  __shared__ __align__(16) ushortT sAh[8192], sAl[8192];  // [128][64]
  __shared__ __align__(16) ushortT sBh[4096], sBl[4096];  // [64][64]
  const int t = threadIdx.x;
  const int w = t >> 6, l = t & 63;
  const int wr = w >> 1, wc = w & 1;

  int id = blockIdx.x;
  int id2 = (id & 7) * 64 + (id >> 3);
  const int mt = id2 >> 4, nt = id2 & 15;
  const int m0 = mt * 128, n0 = nt * 64;

  f32x4 acc[4][2];
#pragma unroll
  for (int i = 0; i < 4; i++)
#pragma unroll
    for (int j = 0; j < 2; j++) acc[i][j] = (f32x4){0.0f, 0.0f, 0.0f, 0.0f};

  const int sr = l >> 3, sg = l & 7;
  const int swz = sg ^ sr;

  for (int kt = 0; kt < 16; ++kt) {
    __syncthreads();
#pragma unroll
    for (int s2 = 0; s2 < 4; s2++) {
      int seg = w * 4 + s2;
      size_t g = (size_t)(m0 + seg * 8 + sr) * ED + kt * 64 + swz * 8;
      gld_lds16(Ah + g, sAh + seg * 512);
      gld_lds16(Al + g, sAl + seg * 512);
    }
#pragma unroll
    for (int s2 = 0; s2 < 2; s2++) {
      int seg = w * 2 + s2;
      size_t g = (size_t)(n0 + seg * 8 + sr) * ED + kt * 64 + swz * 8;
      gld_lds16(Wh + g, sBh + seg * 512);
      gld_lds16(Wl + g, sBl + seg * 512);
    }
    __syncthreads();
#pragma unroll
    for (int ks = 0; ks < 2; ks++) {
      bf16x8 ah[4], al[4], bh[2], bl[2];
      const int G = ks * 4 + (l >> 4);
#pragma unroll
      for (int i = 0; i < 4; i++) {
        int r = wr * 64 + i * 16 + (l & 15);
        int off = r * 64 + ((G ^ (l & 7)) << 3);
        ah[i] = *(const bf16x8*)&sAh[off];
        al[i] = *(const bf16x8*)&sAl[off];
      }
#pragma unroll
      for (int j = 0; j < 2; j++) {
        int r = wc * 32 + j * 16 + (l & 15);
        int off = r * 64 + ((G ^ (l & 7)) << 3);
        bh[j] = *(const bf16x8*)&sBh[off];
        bl[j] = *(const bf16x8*)&sBl[off];
      }
#pragma unroll
      for (int i = 0; i < 4; i++)
#pragma unroll
        for (int j = 0; j < 2; j++) {
          acc[i][j] = mfma16(ah[i], bh[j], acc[i][j]);
          acc[i][j] = mfma16(ah[i], bl[j], acc[i][j]);
          acc[i][j] = mfma16(al[i], bh[j], acc[i][j]);
        }
    }
  }

  const int coln = l & 15, row4 = (l >> 4) * 4;
  float bn[2];
#pragma unroll
  for (int j = 0; j < 2; j++) bn[j] = bias[n0 + wc * 32 + j * 16 + coln];

  if (MODE == 1) {
    float* C = (float*)Cp;
#pragma unroll
    for (int i = 0; i < 4; i++)
#pragma unroll
      for (int j = 0; j < 2; j++) {
        int n = n0 + wc * 32 + j * 16 + coln;
#pragma unroll
        for (int r = 0; r < 4; r++) {
          int m = m0 + wr * 64 + i * 16 + row4 + r;
          C[(size_t)m * ED + n] = acc[i][j][r] + bn[j];
        }
      }
  } else if (MODE == 0) {
    ushortT* Ch = (ushortT*)Cp;
    ushortT* Cl = (ushortT*)C2p;
    const int b_ = m0 >> 11, h_ = n0 >> 6;
#pragma unroll
    for (int i = 0; i < 4; i++)
#pragma unroll
      for (int j = 0; j < 2; j++) {
        int hd = wc * 32 + j * 16 + coln;
#pragma unroll
        for (int r = 0; r < 4; r++) {
          int m = m0 + wr * 64 + i * 16 + row4 + r;
          int s_ = m & 2047;
          float y = acc[i][j][r] + bn[j];
          y = (fabsf(y) >= 0.05f) ? y : 0.0f;
          ushortT hh, ll;
          bsplit(y, hh, ll);
          size_t idx = ((size_t)(b_ * HH + h_) * SS + s_) * HDD + hd;
          Ch[idx] = hh;
          Cl[idx] = ll;
        }
      }
  } else {  // MODE 2: transposed V [B,H,HD,S]
    ushortT* Ch = (ushortT*)Cp;
    ushortT* Cl = (ushortT*)C2p;
    const int b_ = m0 >> 11, h_ = n0 >> 6;
#pragma unroll
    for (int i = 0; i < 4; i++)
#pragma unroll
      for (int j = 0; j < 2; j++) {
        int hd = wc * 32 + j * 16 + coln;
        int s0_ = (m0 + wr * 64 + i * 16 + row4) & 2047;
        ushort4 h4, l4;
#pragma unroll
        for (int r = 0; r < 4; r++) {
          float y = acc[i][j][r] + bn[j];
          y = (fabsf(y) >= 0.05f) ? y : 0.0f;
          ushortT hh, ll;
          bsplit(y, hh, ll);
          ((ushortT*)&h4)[r] = hh;
          ((ushortT*)&l4)[r] = ll;
        }
        size_t idx = ((size_t)(b_ * HH + h_) * HDD + hd) * SS + s0_;
        *(ushort4*)&Ch[idx] = h4;
        *(ushort4*)&Cl[idx] = l4;
      }
  }
}

// ---------- MFMA flash attention: swapped QK^T, in-register P ----------
__device__ __forceinline__ f32x16 mfma32(bf16x8 a, bf16x8 b, f32x16 c) {
  return __builtin_amdgcn_mfma_f32_32x32x16_bf16(a, b, c, 0, 0, 0);
}

// exp + pack one acc (32 q-cols x 16 j-rows) into two PV a-frags
__device__ __forceinline__ void exppack(const f32x16& A, float EC, float& lsum,
                                        bf16x8& paA, bf16x8& paB) {
  float p[16];
#pragma unroll
  for (int r = 0; r < 16; r++) {
    p[r] = exp2f(A[r] * EC);
    lsum += p[r];
  }
  unsigned c0 = pkbf(p[0], p[1]), c1 = pkbf(p[2], p[3]);
  unsigned c2 = pkbf(p[4], p[5]), c3 = pkbf(p[6], p[7]);
  unsigned c4 = pkbf(p[8], p[9]), c5 = pkbf(p[10], p[11]);
  unsigned c6 = pkbf(p[12], p[13]), c7 = pkbf(p[14], p[15]);
  plswap(c0, c2); plswap(c1, c3); plswap(c4, c6); plswap(c5, c7);
  uint4 ta = make_uint4(c0, c1, c2, c3);
  uint4 tb = make_uint4(c4, c5, c6, c7);
  paA = __builtin_bit_cast(bf16x8, ta);
  paB = __builtin_bit_cast(bf16x8, tb);
}

__global__ __launch_bounds__(256, 3) void k_attn(
    const ushortT* __restrict__ Qh, const ushortT* __restrict__ Ql,
    const ushortT* __restrict__ Kh,
    const ushortT* __restrict__ Vh, const ushortT* __restrict__ Vl,
    ushortT* __restrict__ ctxH, ushortT* __restrict__ ctxL) {
  __shared__ __align__(16) ushortT sKh[4096];
  __shared__ __align__(16) ushortT sVh[4096], sVl[4096];

  const int t = threadIdx.x;
  const int w = t >> 6, l = t & 63;
  const int l32 = l & 31, g = l >> 5;

  int id = blockIdx.x;
  int id2 = (id & 7) * 64 + (id >> 3);   // XCD-chunked, bijective (512 = 8*64)
  const int bh = id2 >> 4, qt = id2 & 15;

  const size_t kqbase = (size_t)bh * (SS * HDD);   // Q,K: [bh][s][64]
  const size_t vbase = (size_t)bh * (HDD * SS);    // V^T: [bh][64][s]
  const int q0 = qt * 128 + w * 32;

  // Q fragments (hi/lo) in registers: B-operand of QK^T
  bf16x8 qh[4], ql[4];
  const size_t qrow = kqbase + (size_t)(q0 + l32) * HDD;
#pragma unroll
  for (int ks = 0; ks < 4; ks++) {
    int d0 = ks * 16 + g * 8;
    qh[ks] = *(const bf16x8*)&Qh[qrow + d0];
    ql[ks] = *(const bf16x8*)&Ql[qrow + d0];
  }

  f32x16 octx0, octx1;
#pragma unroll
  for (int i = 0; i < 16; i++) { octx0[i] = 0.0f; octx1[i] = 0.0f; }
  float lsum = 0.0f;

  const float EC = 0.125f * 1.44269504088896f;  // SCALE * log2(e)

  const int srow = l >> 3;               // row within 8-row staging segment
  const int sgr = (l & 7) ^ srow;        // pre-swizzled source granule

  for (int kt = 0; kt < 32; ++kt) {
    const int s0 = kt * 64;
    __syncthreads();
    // stage K, V^T hi, V^T lo via global_load_lds (linear LDS dest, swizzled source)
#pragma unroll
    for (int s2 = 0; s2 < 2; s2++) {
      int seg = w * 2 + s2;
      int row = seg * 8 + srow;
      gld_lds16(Kh + kqbase + (size_t)(s0 + row) * HDD + sgr * 8, sKh + seg * 512);
      gld_lds16(Vh + vbase + (size_t)row * SS + s0 + sgr * 8, sVh + seg * 512);
      gld_lds16(Vl + vbase + (size_t)row * SS + s0 + sgr * 8, sVl + seg * 512);
    }
    __syncthreads();

    // QK^T swapped: acc = mfma(A=K, B=Q) -> lane = q-col, rows = j
    f32x16 acc0, acc1;
#pragma unroll
    for (int i = 0; i < 16; i++) { acc0[i] = 0.0f; acc1[i] = 0.0f; }
#pragma unroll
    for (int ks = 0; ks < 4; ks++) {
      int sw = ((ks * 2 + g) ^ (l32 & 7)) << 3;
      bf16x8 kh0 = *(const bf16x8*)&sKh[l32 * 64 + sw];
      bf16x8 kh1 = *(const bf16x8*)&sKh[(32 + l32) * 64 + sw];
      acc0 = mfma32(kh0, qh[ks], acc0);
      acc0 = mfma32(kh0, ql[ks], acc0);
      acc1 = mfma32(kh1, qh[ks], acc1);
      acc1 = mfma32(kh1, ql[ks], acc1);
    }

    // softmax numerator in registers (no max subtraction: |score*scale| small)
    bf16x8 pa0, pa1, pa2, pa3;
    exppack(acc0, EC, lsum, pa0, pa1);
    exppack(acc1, EC, lsum, pa2, pa3);

    // PV: octx[d-block] += P(a) @ V^T(b)
#pragma unroll
    for (int js = 0; js < 4; js++) {
      bf16x8 pj = js == 0 ? pa0 : js == 1 ? pa1 : js == 2 ? pa2 : pa3;
      int vsw = ((js * 2 + g) ^ (l32 & 7)) << 3;
      bf16x8 vh0 = *(const bf16x8*)&sVh[l32 * 64 + vsw];
      bf16x8 vl0 = *(const bf16x8*)&sVl[l32 * 64 + vsw];
      bf16x8 vh1 = *(const bf16x8*)&sVh[(32 + l32) * 64 + vsw];
      bf16x8 vl1 = *(const bf16x8*)&sVl[(32 + l32) * 64 + vsw];
      octx0 = mfma32(pj, vh0, octx0);
      octx0 = mfma32(pj, vl0, octx0);
      octx1 = mfma32(pj, vh1, octx1);
      octx1 = mfma32(pj, vl1, octx1);
    }
  }

  // lsum: lane(q, g) holds partial; combine halves, then broadcast by q
  float ls = lsum + __shfl_xor(lsum, 32, 64);

  const int b_ = bh >> 4, h_ = bh & 15;
#pragma unroll
  for (int r = 0; r < 16; r++) {
    int q = (r & 3) + 8 * (r >> 2) + 4 * g;
    float inv = 1.0f / __shfl(ls, q, 64);
    size_t base = ((size_t)(b_ * SS + q0 + q)) * ED + h_ * HDD;
    ushortT hh, ll;
    bsplit(octx0[r] * inv, hh, ll);
    ctxH[base + l32] = hh;
    ctxL[base + l32] = ll;
    bsplit(octx1[r] * inv, hh, ll);
    ctxH[base + 32 + l32] = hh;
    ctxL[base + 32 + l32] = ll;
  }
}

extern "C" void kernel_launch(void* const* d_in, const int* in_sizes, int n_in,
                              void* d_out, int out_size, void* d_ws, size_t ws_size,
                              hipStream_t stream) {
  const float* query = (const float*)d_in[0];
  const float* key   = (const float*)d_in[1];
  const float* value = (const float*)d_in[2];
  const float* Wq = (const float*)d_in[3];
  const float* bq = (const float*)d_in[4];
  const float* Wk = (const float*)d_in[5];
  const float* bk = (const float*)d_in[6];
  const float* Wv = (const float*)d_in[7];
  const float* bv = (const float*)d_in[8];
  const float* Wo = (const float*)d_in[9];
  const float* bo = (const float*)d_in[10];
  const float* lng = (const float*)d_in[11];
  const float* lnb = (const float*)d_in[12];
  float* out = (float*)d_out;

  if (ws_size < (size_t)WS_NEEDED) {
    fprintf(stderr, "kernel_launch: ws too small (%zu < %u)\n", ws_size, WS_NEEDED);
    return;
  }

  ushortT* wsu = (ushortT*)d_ws;
  ushortT* Whi = wsu + U_WHI;
  ushortT* Wlo = wsu + U_WLO;
  ushortT* Abh = wsu + U_AH;
  ushortT* Abl = wsu + U_AL;
  ushortT* Bbh = wsu + U_BH;
  ushortT* Bbl = wsu + U_BL;
  ushortT* Qhp = wsu + U_QH;
  ushortT* Qlp = wsu + U_QL;
  ushortT* Khp = wsu + U_KH;
  ushortT* Klp = wsu + U_KL;
  ushortT* Vhp = wsu + U_VH;
  ushortT* Vlp = wsu + U_VL;

  char* wsb = (char*)d_ws;
  unsigned* histG = (unsigned*)(wsb + HIST_OFF);
  unsigned long long* sAbs = (unsigned long long*)(wsb + ABS_OFF);
  unsigned long long* sMsk = (unsigned long long*)(wsb + MSK_OFF);
  unsigned* sCnt = (unsigned*)(wsb + CNT_OFF);

  // zero histograms + integer accumulators (replay-safe)
  hipMemsetAsync(histG, 0, SMALL_BYTES, stream);

  dim3 gW(256, 4);
  k_wstats<<<gW, 256, 0, stream>>>(Wq, Wk, Wv, Wo, sAbs);
  k_masked<<<gW, 256, 0, stream>>>(Wq, Wk, Wv, Wo, sAbs, sMsk, sCnt);
  for (int pass = 0; pass < 4; ++pass)
    k_hist<<<gW, 256, 0, stream>>>(Wq, Wk, Wv, Wo, sAbs, sMsk, sCnt, histG, pass);
  k_weff<<<dim3(1024, 4), 256, 0, stream>>>(Wq, Wk, Wv, Wo, sAbs, sMsk, sCnt, histG,
                                            Whi, Wlo);

  // LN(query) -> A, split(key) -> B
  k_pre<<<dim3(MROWS, 2), 256, 0, stream>>>(query, key, lng, lnb, Abh, Abl, Bbh, Bbl);

  k_gemm_mfma<0><<<512, 256, 0, stream>>>(Abh, Abl, Whi + 0 * NW_ELEM, Wlo + 0 * NW_ELEM,
                                          bq, Qhp, Qlp);
  k_gemm_mfma<0><<<512, 256, 0, stream>>>(Bbh, Bbl, Whi + 1 * NW_ELEM, Wlo + 1 * NW_ELEM,
                                          bk, Khp, Klp);
  // value split -> A (A free after Q gemm), then V gemm (transposed out)
  k_splitv<<<4096, 256, 0, stream>>>(value, Abh, Abl);
  k_gemm_mfma<2><<<512, 256, 0, stream>>>(Abh, Abl, Whi + 2 * NW_ELEM, Wlo + 2 * NW_ELEM,
                                          bv, Vhp, Vlp);

  // attention -> ctx (into A)
  k_attn<<<512, 256, 0, stream>>>(Qhp, Qlp, Khp, Vhp, Vlp, Abh, Abl);

  // out projection
  k_gemm_mfma<1><<<512, 256, 0, stream>>>(Abh, Abl, Whi + 3 * NW_ELEM, Wlo + 3 * NW_ELEM,
                                          bo, out, nullptr);
}

// Round 5
// 257.145 us; speedup vs baseline: 4.3955x; 1.1416x over previous
//
#include <hip/hip_runtime.h>
#include <stdio.h>
#include <stdint.h>

// Problem constants
#define BB 2
#define SS 2048
#define ED 1024
#define HH 16
#define HDD 64
#define MROWS 4096            // BB*SS
#define NW_ELEM 1048576u      // ED*ED

typedef unsigned short ushortT;
typedef __attribute__((ext_vector_type(8))) short bf16x8;
typedef __attribute__((ext_vector_type(4))) float f32x4;
typedef __attribute__((ext_vector_type(16))) float f32x16;

// ws layout (ushort elems from base)
#define U_WHI 0u
#define U_WLO 4194304u
#define U_AH  8388608u
#define U_BH  12582912u
#define U_QH  16777216u
#define U_KH  20971520u
#define U_VH  25165824u
#define U_CH  29360128u
#define U_CL  33554432u
// byte offsets for small buffers (after 72MB of ushort regions)
#define SMALL_OFF  75497472u
#define HIST_OFF   SMALL_OFF                 // 4 passes * 4 w * 256 bins * 4B = 16384
#define ABS_OFF    (SMALL_OFF + 16384u)      // 4 * 8B
#define MSK_OFF    (ABS_OFF + 32u)           // 4 * 8B
#define CNT_OFF    (MSK_OFF + 32u)           // 4 * 4B
#define SMALL_BYTES 16464u
#define WS_NEEDED  (SMALL_OFF + SMALL_BYTES)

#define SC44 17592186044416.0f               // 2^44
#define INV44 (1.0 / 17592186044416.0)

__device__ __forceinline__ const float* wsel(int w, const float* W0, const float* W1,
                                             const float* W2, const float* W3) {
  return w == 0 ? W0 : w == 1 ? W1 : w == 2 ? W2 : W3;
}

// bf16 RTNE helpers
__device__ __forceinline__ ushortT f2bf(float x) {
  unsigned u = __float_as_uint(x);
  unsigned r = (u + 0x7FFFu + ((u >> 16) & 1u)) >> 16;
  return (ushortT)r;
}
__device__ __forceinline__ float bf2f(ushortT b) {
  return __uint_as_float(((unsigned)b) << 16);
}
__device__ __forceinline__ void bsplit(float x, ushortT& h, ushortT& l) {
  ushortT hb = f2bf(x);
  float hf = bf2f(hb);
  h = hb;
  l = f2bf(x - hf);
}
// packed bf16 convert (RTNE) and cross-row swap
__device__ __forceinline__ unsigned pkbf(float a, float b) {
  unsigned r;
  asm("v_cvt_pk_bf16_f32 %0, %1, %2" : "=v"(r) : "v"(a), "v"(b));
  return r;
}
__device__ __forceinline__ void plswap(unsigned& a, unsigned& b) {
  asm("v_permlane32_swap_b32 %0, %1" : "+v"(a), "+v"(b));
}

// async global->LDS, 16B/lane; LDS dest = wave-uniform base + lane*16
__device__ __forceinline__ void gld_lds16(const ushortT* g, ushortT* s) {
  __builtin_amdgcn_global_load_lds((__attribute__((address_space(1))) void*)g,
                                   (__attribute__((address_space(3))) void*)s, 16, 0, 0);
}

__device__ __forceinline__ float get_thr(const unsigned long long* sAbs, int w) {
  return 0.7f * (float)((double)sAbs[w] * INV44 / 1048576.0);
}
__device__ __forceinline__ float get_scale(const unsigned long long* sMsk,
                                           const unsigned* cnt, int w) {
  double s = (double)sMsk[w] * INV44;
  return (float)s / fmaxf((float)cnt[w], 1.0f);
}

// parallel radix-select step: suffix-scan hist, pick bucket, update (k, prefix)
__device__ __forceinline__ void scan_sel(const unsigned* hist, unsigned& k, unsigned& prefix,
                                         unsigned* sh, int t) {
  sh[t] = hist[t];
  __syncthreads();
  for (int off = 1; off < 256; off <<= 1) {
    unsigned add = (t + off < 256) ? sh[t + off] : 0u;
    __syncthreads();
    sh[t] += add;
    __syncthreads();
  }
  int sel = __syncthreads_count((int)(sh[t] >= k)) - 1;
  unsigned suf = sh[sel];
  k -= (suf - hist[sel]);
  prefix = (prefix << 8) | (unsigned)sel;
  __syncthreads();
}

// ---------- pass 1: sum |W| (integer fixed-point atomics, deterministic) ----------
__global__ __launch_bounds__(256) void k_wstats(const float* W0, const float* W1,
                                                const float* W2, const float* W3,
                                                unsigned long long* sAbs) {
  const int w = blockIdx.y, t = threadIdx.x;
  const float* W = wsel(w, W0, W1, W2, W3) + blockIdx.x * 4096;
  unsigned long long s = 0;
#pragma unroll
  for (int r = 0; r < 4; r++) {
    float4 v = *(const float4*)(W + (t + 256 * r) * 4);
    s += (unsigned long long)(fabsf(v.x) * SC44);
    s += (unsigned long long)(fabsf(v.y) * SC44);
    s += (unsigned long long)(fabsf(v.z) * SC44);
    s += (unsigned long long)(fabsf(v.w) * SC44);
  }
  __shared__ unsigned long long sd[256];
  sd[t] = s;
  __syncthreads();
  for (int off = 128; off > 0; off >>= 1) {
    if (t < off) sd[t] += sd[t + off];
    __syncthreads();
  }
  if (!t) atomicAdd(&sAbs[w], sd[0]);
}

// ---------- pass 2: masked sum/count ----------
__global__ __launch_bounds__(256) void k_masked(const float* W0, const float* W1,
                                                const float* W2, const float* W3,
                                                const unsigned long long* sAbs,
                                                unsigned long long* sMsk, unsigned* sCnt) {
  const int w = blockIdx.y, t = threadIdx.x;
  const float thr = get_thr(sAbs, w);
  const float* W = wsel(w, W0, W1, W2, W3) + blockIdx.x * 4096;
  unsigned long long s = 0;
  unsigned c = 0;
#pragma unroll
  for (int r = 0; r < 4; r++) {
    float4 v = *(const float4*)(W + (t + 256 * r) * 4);
    float xs[4] = {v.x, v.y, v.z, v.w};
#pragma unroll
    for (int q = 0; q < 4; q++) {
      float a = fabsf(xs[q]);
      if (a > thr) { s += (unsigned long long)(a * SC44); c++; }
    }
  }
  __shared__ unsigned long long sd[256];
  __shared__ unsigned sc[256];
  sd[t] = s; sc[t] = c;
  __syncthreads();
  for (int off = 128; off > 0; off >>= 1) {
    if (t < off) { sd[t] += sd[t + off]; sc[t] += sc[t + off]; }
    __syncthreads();
  }
  if (!t) { atomicAdd(&sMsk[w], sd[0]); atomicAdd(&sCnt[w], sc[0]); }
}

// ---------- radix histogram pass ----------
__global__ __launch_bounds__(256) void k_hist(const float* W0, const float* W1,
                                              const float* W2, const float* W3,
                                              const unsigned long long* sAbs,
                                              const unsigned long long* sMsk,
                                              const unsigned* sCnt,
                                              unsigned* histG, int pass) {
  const int w = blockIdx.y, t = threadIdx.x;
  __shared__ unsigned sh[256];
  __shared__ unsigned h[256];
  const float thr = get_thr(sAbs, w);
  const float scale = get_scale(sMsk, sCnt, w);
  unsigned k = (w == 3) ? 104857u : 52428u, prefix = 0u;
  for (int pp = 0; pp < pass; pp++)
    scan_sel(histG + (pp * 4 + w) * 256, k, prefix, sh, t);

  h[t] = 0;
  __syncthreads();
  const float* W = wsel(w, W0, W1, W2, W3) + blockIdx.x * 4096;
  const int shift1 = 32 - 8 * pass;
  const int shift2 = 24 - 8 * pass;
#pragma unroll
  for (int r = 0; r < 4; r++) {
    float4 v = *(const float4*)(W + (t + 256 * r) * 4);
    float xs[4] = {v.x, v.y, v.z, v.w};
#pragma unroll
    for (int q = 0; q < 4; q++) {
      float x = xs[q];
      float a = fabsf(x);
      float wq = (a > thr) ? copysignf(scale, x) : 0.0f;
      unsigned bits = __float_as_uint(fabsf(x - wq));
      if (pass == 0) {
        atomicAdd(&h[bits >> 24], 1u);
      } else {
        if ((bits >> shift1) == prefix)
          atomicAdd(&h[(bits >> shift2) & 255u], 1u);
      }
    }
  }
  __syncthreads();
  if (h[t]) atomicAdd(&histG[(pass * 4 + w) * 256 + t], h[t]);
}

// ---------- build W_eff, split to bf16 hi/lo ----------
__global__ __launch_bounds__(256) void k_weff(const float* W0, const float* W1,
                                              const float* W2, const float* W3,
                                              const unsigned long long* sAbs,
                                              const unsigned long long* sMsk,
                                              const unsigned* sCnt,
                                              const unsigned* histG,
                                              ushortT* Whi, ushortT* Wlo) {
  const int w = blockIdx.y, t = threadIdx.x;
  __shared__ unsigned sh[256];
  const float thr = get_thr(sAbs, w);
  const float scale = get_scale(sMsk, sCnt, w);
  unsigned k = (w == 3) ? 104857u : 52428u, kth = 0u;
  for (int pp = 0; pp < 4; pp++)
    scan_sel(histG + (pp * 4 + w) * 256, k, kth, sh, t);

  const unsigned idx = (blockIdx.x * 256 + t) * 4;
  const float* W = wsel(w, W0, W1, W2, W3);
  float4 v = *(const float4*)(W + idx);
  float xs[4] = {v.x, v.y, v.z, v.w};
  ushort4 h4, l4;
#pragma unroll
  for (int c = 0; c < 4; c++) {
    float x = xs[c];
    float a = fabsf(x);
    float wq = (a > thr) ? copysignf(scale, x) : 0.0f;
    float res = x - wq;
    unsigned bits = __float_as_uint(fabsf(res));
    float we = wq + ((bits >= kth) ? res : 0.0f);
    ushortT hh, ll;
    bsplit(we, hh, ll);
    ((ushortT*)&h4)[c] = hh;
    ((ushortT*)&l4)[c] = ll;
  }
  *(ushort4*)&Whi[(size_t)w * NW_ELEM + idx] = h4;
  *(ushort4*)&Wlo[(size_t)w * NW_ELEM + idx] = l4;
}

// ---------- fused: LayerNorm(query) -> Ah ; key -> Bh (bf16 hi only) ----------
__global__ __launch_bounds__(256) void k_pre(const float* __restrict__ query,
                                             const float* __restrict__ key,
                                             const float* __restrict__ g,
                                             const float* __restrict__ b,
                                             ushortT* __restrict__ Ah,
                                             ushortT* __restrict__ Bh) {
  const int t = threadIdx.x;
  if (blockIdx.y == 0) {
    const int row = blockIdx.x;
    __shared__ float red[8];
    float4 v = *(const float4*)&query[(size_t)row * ED + t * 4];
    float s = v.x + v.y + v.z + v.w;
#pragma unroll
    for (int m = 32; m; m >>= 1) s += __shfl_xor(s, m, 64);
    if ((t & 63) == 0) red[t >> 6] = s;
    __syncthreads();
    float mu = (red[0] + red[1] + red[2] + red[3]) * (1.0f / 1024.0f);
    float dx = v.x - mu, dy = v.y - mu, dz = v.z - mu, dw = v.w - mu;
    float s2 = dx * dx + dy * dy + dz * dz + dw * dw;
#pragma unroll
    for (int m = 32; m; m >>= 1) s2 += __shfl_xor(s2, m, 64);
    if ((t & 63) == 0) red[4 + (t >> 6)] = s2;
    __syncthreads();
    float var = (red[4] + red[5] + red[6] + red[7]) * (1.0f / 1024.0f);
    float inv = rsqrtf(var + 1e-5f);
    float4 gg = *(const float4*)&g[t * 4];
    float4 bb = *(const float4*)&b[t * 4];
    float ys[4] = {dx * inv * gg.x + bb.x, dy * inv * gg.y + bb.y,
                   dz * inv * gg.z + bb.z, dw * inv * gg.w + bb.w};
    ushort4 h4;
#pragma unroll
    for (int c = 0; c < 4; c++) ((ushortT*)&h4)[c] = f2bf(ys[c]);
    *(ushort4*)&Ah[(size_t)row * ED + t * 4] = h4;
  } else {
    const int i = (blockIdx.x * 256 + t) * 4;
    float4 v = *(const float4*)&key[i];
    ushort4 h4;
    h4.x = f2bf(v.x); h4.y = f2bf(v.y); h4.z = f2bf(v.z); h4.w = f2bf(v.w);
    *(ushort4*)&Bh[i] = h4;
  }
}

// ---------- fp32 -> bf16 hi (value) ----------
__global__ __launch_bounds__(256) void k_splith(const float* __restrict__ X,
                                                ushortT* __restrict__ H) {
  const int i = (blockIdx.x * 256 + threadIdx.x) * 4;
  float4 v = *(const float4*)&X[i];
  ushort4 h4;
  h4.x = f2bf(v.x); h4.y = f2bf(v.y); h4.z = f2bf(v.z); h4.w = f2bf(v.w);
  *(ushort4*)&H[i] = h4;
}

// ---------- bf16 MFMA GEMM: C = A @ W^T + bias ----------
// BM=128 BN=64 BK=64; 4 waves, wave tile 64x32 (4x2 frags of 16x16x32)
// ALO: A has lo part (3rd MFMA ah*wl? no: ah*bh + [WLO] ah*bl + [ALO] al*bh)
// MODE 0: route -> bf16 hi [B,H,S,HD]; MODE 1: fp32 [M,N]; MODE 2: route -> bf16 hi [B,H,HD,S]
__device__ __forceinline__ f32x4 mfma16(bf16x8 a, bf16x8 b, f32x4 c) {
  return __builtin_amdgcn_mfma_f32_16x16x32_bf16(a, b, c, 0, 0, 0);
}

template <int MODE, bool ALO, bool WLO, bool DBUF>
__global__ __launch_bounds__(256, 2) void k_gemm(
    const ushortT* __restrict__ Ah, const ushortT* __restrict__ Al,
    const ushortT* __restrict__ Wh, const ushortT* __restrict__ Wl,
    const float* __restrict__ bias, ushortT* Cp, float* Cf) {
  constexpr int NB = DBUF ? 2 : 1;
  __shared__ __align__(16) ushortT sAh[NB * 8192];
  __shared__ __align__(16) ushortT sAl[ALO ? NB * 8192 : 8];
  __shared__ __align__(16) ushortT sBh[NB * 4096];
  __shared__ __align__(16) ushortT sBl[WLO ? NB * 4096 : 8];
  const int t = threadIdx.x;
  const int w = t >> 6, l = t & 63;
  const int wr = w >> 1, wc = w & 1;

  int id = blockIdx.x;
  int id2 = (id & 7) * 64 + (id >> 3);   // XCD-chunked (512 = 8*64, bijective)
  const int mt = id2 >> 4, nt = id2 & 15;
  const int m0 = mt * 128, n0 = nt * 64;

  const int sr = l >> 3, sg = l & 7;
  const int swz = sg ^ sr;               // pre-swizzled source granule

  auto stage = [&](int kt, int buf) {
#pragma unroll
    for (int s2 = 0; s2 < 4; s2++) {
      int seg = w * 4 + s2;
      size_t g = (size_t)(m0 + seg * 8 + sr) * ED + kt * 64 + swz * 8;
      gld_lds16(Ah + g, sAh + buf * 8192 + seg * 512);
      if constexpr (ALO) gld_lds16(Al + g, sAl + buf * 8192 + seg * 512);
    }
#pragma unroll
    for (int s2 = 0; s2 < 2; s2++) {
      int seg = w * 2 + s2;
      size_t g = (size_t)(n0 + seg * 8 + sr) * ED + kt * 64 + swz * 8;
      gld_lds16(Wh + g, sBh + buf * 4096 + seg * 512);
      if constexpr (WLO) gld_lds16(Wl + g, sBl + buf * 4096 + seg * 512);
    }
  };

  f32x4 acc[4][2];
#pragma unroll
  for (int i = 0; i < 4; i++)
#pragma unroll
    for (int j = 0; j < 2; j++) acc[i][j] = (f32x4){0.0f, 0.0f, 0.0f, 0.0f};

  auto compute = [&](int buf) {
#pragma unroll
    for (int ks = 0; ks < 2; ks++) {
      bf16x8 ah[4], al[4], bh[2], bl[2];
      const int G = ks * 4 + (l >> 4);
#pragma unroll
      for (int i = 0; i < 4; i++) {
        int r = wr * 64 + i * 16 + (l & 15);
        int off = buf * 8192 + r * 64 + ((G ^ (l & 7)) << 3);
        ah[i] = *(const bf16x8*)&sAh[off];
        if constexpr (ALO) al[i] = *(const bf16x8*)&sAl[off];
      }
#pragma unroll
      for (int j = 0; j < 2; j++) {
        int r = wc * 32 + j * 16 + (l & 15);
        int off = buf * 4096 + r * 64 + ((G ^ (l & 7)) << 3);
        bh[j] = *(const bf16x8*)&sBh[off];
        if constexpr (WLO) bl[j] = *(const bf16x8*)&sBl[off];
      }
#pragma unroll
      for (int i = 0; i < 4; i++)
#pragma unroll
        for (int j = 0; j < 2; j++) {
          acc[i][j] = mfma16(ah[i], bh[j], acc[i][j]);
          if constexpr (WLO) acc[i][j] = mfma16(ah[i], bl[j], acc[i][j]);
          if constexpr (ALO) acc[i][j] = mfma16(al[i], bh[j], acc[i][j]);
        }
    }
  };

  if constexpr (DBUF) {
    stage(0, 0);
    __syncthreads();                     // implicit vmcnt(0) drain
    for (int kt = 0; kt < 16; ++kt) {
      if (kt < 15) stage(kt + 1, (kt + 1) & 1);
      compute(kt & 1);
      __syncthreads();
    }
  } else {
    for (int kt = 0; kt < 16; ++kt) {
      __syncthreads();
      stage(kt, 0);
      __syncthreads();
      compute(0);
    }
  }

  // epilogue: D layout col = l&15, row = (l>>4)*4 + reg
  const int coln = l & 15, row4 = (l >> 4) * 4;
  float bn[2];
#pragma unroll
  for (int j = 0; j < 2; j++) bn[j] = bias[n0 + wc * 32 + j * 16 + coln];

  if constexpr (MODE == 1) {
#pragma unroll
    for (int i = 0; i < 4; i++)
#pragma unroll
      for (int j = 0; j < 2; j++) {
        int n = n0 + wc * 32 + j * 16 + coln;
#pragma unroll
        for (int r = 0; r < 4; r++) {
          int m = m0 + wr * 64 + i * 16 + row4 + r;
          Cf[(size_t)m * ED + n] = acc[i][j][r] + bn[j];
        }
      }
  } else if constexpr (MODE == 0) {
    const int b_ = m0 >> 11, h_ = n0 >> 6;
#pragma unroll
    for (int i = 0; i < 4; i++)
#pragma unroll
      for (int j = 0; j < 2; j++) {
        int hd = wc * 32 + j * 16 + coln;
#pragma unroll
        for (int r = 0; r < 4; r++) {
          int m = m0 + wr * 64 + i * 16 + row4 + r;
          int s_ = m & 2047;
          float y = acc[i][j][r] + bn[j];
          y = (fabsf(y) >= 0.05f) ? y : 0.0f;
          Cp[((size_t)(b_ * HH + h_) * SS + s_) * HDD + hd] = f2bf(y);
        }
      }
  } else {  // MODE 2: transposed V [B,H,HD,S]
    const int b_ = m0 >> 11, h_ = n0 >> 6;
#pragma unroll
    for (int i = 0; i < 4; i++)
#pragma unroll
      for (int j = 0; j < 2; j++) {
        int hd = wc * 32 + j * 16 + coln;
        int s0_ = (m0 + wr * 64 + i * 16 + row4) & 2047;
        ushort4 h4;
#pragma unroll
        for (int r = 0; r < 4; r++) {
          float y = acc[i][j][r] + bn[j];
          y = (fabsf(y) >= 0.05f) ? y : 0.0f;
          ((ushortT*)&h4)[r] = f2bf(y);
        }
        *(ushort4*)&Cp[((size_t)(b_ * HH + h_) * HDD + hd) * SS + s0_] = h4;
      }
  }
}

// ---------- MFMA flash attention: pure bf16, swapped QK^T, in-reg P, 2-phase ----------
__device__ __forceinline__ f32x16 mfma32(bf16x8 a, bf16x8 b, f32x16 c) {
  return __builtin_amdgcn_mfma_f32_32x32x16_bf16(a, b, c, 0, 0, 0);
}

// exp + pack one acc (32 q-cols x 16 j-rows) into two PV a-frags
__device__ __forceinline__ void exppack(const f32x16& A, float EC, float& lsum,
                                        bf16x8& paA, bf16x8& paB) {
  float p[16];
#pragma unroll
  for (int r = 0; r < 16; r++) {
    p[r] = exp2f(A[r] * EC);
    lsum += p[r];
  }
  unsigned c0 = pkbf(p[0], p[1]), c1 = pkbf(p[2], p[3]);
  unsigned c2 = pkbf(p[4], p[5]), c3 = pkbf(p[6], p[7]);
  unsigned c4 = pkbf(p[8], p[9]), c5 = pkbf(p[10], p[11]);
  unsigned c6 = pkbf(p[12], p[13]), c7 = pkbf(p[14], p[15]);
  plswap(c0, c2); plswap(c1, c3); plswap(c4, c6); plswap(c5, c7);
  uint4 ta = make_uint4(c0, c1, c2, c3);
  uint4 tb = make_uint4(c4, c5, c6, c7);
  paA = __builtin_bit_cast(bf16x8, ta);
  paB = __builtin_bit_cast(bf16x8, tb);
}

__global__ __launch_bounds__(256, 2) void k_attn(
    const ushortT* __restrict__ Qh, const ushortT* __restrict__ Kh,
    const ushortT* __restrict__ Vh,
    ushortT* __restrict__ ctxH, ushortT* __restrict__ ctxL) {
  __shared__ __align__(16) ushortT sK[2 * 4096];
  __shared__ __align__(16) ushortT sV[2 * 4096];

  const int t = threadIdx.x;
  const int w = t >> 6, l = t & 63;
  const int l32 = l & 31, g = l >> 5;

  int id = blockIdx.x;
  int id2 = (id & 7) * 64 + (id >> 3);   // XCD-chunked, bijective (512 = 8*64)
  const int bh = id2 >> 4, qt = id2 & 15;

  const size_t kqbase = (size_t)bh * (SS * HDD);   // Q,K: [bh][s][64]
  const size_t vbase = (size_t)bh * (HDD * SS);    // V^T: [bh][64][s]
  const int q0 = qt * 128 + w * 32;

  // Q fragments in registers: B-operand of swapped QK^T
  bf16x8 qh[4];
  const size_t qrow = kqbase + (size_t)(q0 + l32) * HDD;
#pragma unroll
  for (int ks = 0; ks < 4; ks++) qh[ks] = *(const bf16x8*)&Qh[qrow + ks * 16 + g * 8];

  f32x16 octx0, octx1;
#pragma unroll
  for (int i = 0; i < 16; i++) { octx0[i] = 0.0f; octx1[i] = 0.0f; }
  float lsum = 0.0f;

  const float EC = 0.125f * 1.44269504088896f;  // SCALE * log2(e)

  const int srow = l >> 3;               // row within 8-row staging segment
  const int sgr = (l & 7) ^ srow;        // pre-swizzled source granule

  auto stageA = [&](int kt, int buf) {
    const int s0 = kt * 64;
#pragma unroll
    for (int s2 = 0; s2 < 2; s2++) {
      int seg = w * 2 + s2;
      int row = seg * 8 + srow;
      gld_lds16(Kh + kqbase + (size_t)(s0 + row) * HDD + sgr * 8, sK + buf * 4096 + seg * 512);
      gld_lds16(Vh + vbase + (size_t)row * SS + s0 + sgr * 8, sV + buf * 4096 + seg * 512);
    }
  };

  stageA(0, 0);
  __syncthreads();                       // implicit vmcnt(0) drain

  for (int kt = 0; kt < 32; ++kt) {
    if (kt < 31) stageA(kt + 1, (kt + 1) & 1);
    const ushortT* cK = sK + (kt & 1) * 4096;
    const ushortT* cV = sV + (kt & 1) * 4096;

    // QK^T swapped: acc = mfma(A=K, B=Q) -> lane = q-col, rows = j
    f32x16 acc0, acc1;
#pragma unroll
    for (int i = 0; i < 16; i++) { acc0[i] = 0.0f; acc1[i] = 0.0f; }
#pragma unroll
    for (int ks = 0; ks < 4; ks++) {
      int sw = ((ks * 2 + g) ^ (l32 & 7)) << 3;
      bf16x8 kh0 = *(const bf16x8*)&cK[l32 * 64 + sw];
      bf16x8 kh1 = *(const bf16x8*)&cK[(32 + l32) * 64 + sw];
      acc0 = mfma32(kh0, qh[ks], acc0);
      acc1 = mfma32(kh1, qh[ks], acc1);
    }

    // softmax numerator in registers (no max subtraction: |score*scale| small)
    bf16x8 pa0, pa1, pa2, pa3;
    exppack(acc0, EC, lsum, pa0, pa1);
    exppack(acc1, EC, lsum, pa2, pa3);

    // PV: octx[d-block] += P(a) @ V^T(b)
#pragma unroll
    for (int js = 0; js < 4; js++) {
      bf16x8 pj = js == 0 ? pa0 : js == 1 ? pa1 : js == 2 ? pa2 : pa3;
      int vsw = ((js * 2 + g) ^ (l32 & 7)) << 3;
      bf16x8 vh0 = *(const bf16x8*)&cV[l32 * 64 + vsw];
      bf16x8 vh1 = *(const bf16x8*)&cV[(32 + l32) * 64 + vsw];
      octx0 = mfma32(pj, vh0, octx0);
      octx1 = mfma32(pj, vh1, octx1);
    }
    __syncthreads();                     // drains prefetch vmcnt; LDS reuse safe
  }

  // lsum: lane(q, g) holds partial; combine halves, then broadcast by q
  float ls = lsum + __shfl_xor(lsum, 32, 64);

  const int b_ = bh >> 4, h_ = bh & 15;
#pragma unroll
  for (int r = 0; r < 16; r++) {
    int q = (r & 3) + 8 * (r >> 2) + 4 * g;
    float inv = 1.0f / __shfl(ls, q, 64);
    size_t base = ((size_t)(b_ * SS + q0 + q)) * ED + h_ * HDD;
    ushortT hh, ll;
    bsplit(octx0[r] * inv, hh, ll);
    ctxH[base + l32] = hh;
    ctxL[base + l32] = ll;
    bsplit(octx1[r] * inv, hh, ll);
    ctxH[base + 32 + l32] = hh;
    ctxL[base + 32 + l32] = ll;
  }
}

extern "C" void kernel_launch(void* const* d_in, const int* in_sizes, int n_in,
                              void* d_out, int out_size, void* d_ws, size_t ws_size,
                              hipStream_t stream) {
  const float* query = (const float*)d_in[0];
  const float* key   = (const float*)d_in[1];
  const float* value = (const float*)d_in[2];
  const float* Wq = (const float*)d_in[3];
  const float* bq = (const float*)d_in[4];
  const float* Wk = (const float*)d_in[5];
  const float* bk = (const float*)d_in[6];
  const float* Wv = (const float*)d_in[7];
  const float* bv = (const float*)d_in[8];
  const float* Wo = (const float*)d_in[9];
  const float* bo = (const float*)d_in[10];
  const float* lng = (const float*)d_in[11];
  const float* lnb = (const float*)d_in[12];
  float* out = (float*)d_out;

  if (ws_size < (size_t)WS_NEEDED) {
    fprintf(stderr, "kernel_launch: ws too small (%zu < %u)\n", ws_size, WS_NEEDED);
    return;
  }

  ushortT* wsu = (ushortT*)d_ws;
  ushortT* Whi = wsu + U_WHI;
  ushortT* Wlo = wsu + U_WLO;
  ushortT* Abh = wsu + U_AH;
  ushortT* Bbh = wsu + U_BH;
  ushortT* Qhp = wsu + U_QH;
  ushortT* Khp = wsu + U_KH;
  ushortT* Vhp = wsu + U_VH;
  ushortT* Chp = wsu + U_CH;
  ushortT* Clp = wsu + U_CL;

  char* wsb = (char*)d_ws;
  unsigned* histG = (unsigned*)(wsb + HIST_OFF);
  unsigned long long* sAbs = (unsigned long long*)(wsb + ABS_OFF);
  unsigned long long* sMsk = (unsigned long long*)(wsb + MSK_OFF);
  unsigned* sCnt = (unsigned*)(wsb + CNT_OFF);

  hipMemsetAsync(histG, 0, SMALL_BYTES, stream);

  dim3 gW(256, 4);
  k_wstats<<<gW, 256, 0, stream>>>(Wq, Wk, Wv, Wo, sAbs);
  k_masked<<<gW, 256, 0, stream>>>(Wq, Wk, Wv, Wo, sAbs, sMsk, sCnt);
  for (int pass = 0; pass < 4; ++pass)
    k_hist<<<gW, 256, 0, stream>>>(Wq, Wk, Wv, Wo, sAbs, sMsk, sCnt, histG, pass);
  k_weff<<<dim3(1024, 4), 256, 0, stream>>>(Wq, Wk, Wv, Wo, sAbs, sMsk, sCnt, histG,
                                            Whi, Wlo);

  // LN(query) -> Ah, split(key) -> Bh
  k_pre<<<dim3(MROWS, 2), 256, 0, stream>>>(query, key, lng, lnb, Abh, Bbh);

  // Q/K GEMMs: pure bf16 (A-hi x W-hi), double-buffered
  k_gemm<0, false, false, true><<<512, 256, 0, stream>>>(
      Abh, nullptr, Whi + 0 * NW_ELEM, nullptr, bq, Qhp, nullptr);
  k_gemm<0, false, false, true><<<512, 256, 0, stream>>>(
      Bbh, nullptr, Whi + 1 * NW_ELEM, nullptr, bk, Khp, nullptr);

  // V: split(value) -> Ah (reuse), GEMM A-hi x (W-hi + W-lo), transposed out
  k_splith<<<4096, 256, 0, stream>>>(value, Abh);
  k_gemm<2, false, true, true><<<512, 256, 0, stream>>>(
      Abh, nullptr, Whi + 2 * NW_ELEM, Wlo + 2 * NW_ELEM, bv, Vhp, nullptr);

  // attention -> ctx hi/lo
  k_attn<<<512, 256, 0, stream>>>(Qhp, Khp, Vhp, Chp, Clp);

  // out projection: split-A x split-W (3 MFMA), single-buffered
  k_gemm<1, true, true, false><<<512, 256, 0, stream>>>(
      Chp, Clp, Whi + 3 * NW_ELEM, Wlo + 3 * NW_ELEM, bo, nullptr, out);
}